// Round 1
// baseline (686.855 us; speedup 1.0000x reference)
//
#include <hip/hip_runtime.h>
#include <math.h>

#define N_NODES 32768
#define N_EDGES 524288
#define IN_F    256
#define OUT_F   128
#define NB      4

// ---------------------------------------------------------------------------
// Edge dtype detection: reference says int64; harness doc says "integer ->
// const int*". Detect at runtime: if the odd 32-bit words of the first 64
// presumed-int64 entries are all zero -> int64 layout, else int32.
// ---------------------------------------------------------------------------
__global__ void detect_kernel(const int* __restrict__ ei, int* __restrict__ flag) {
    int t = threadIdx.x;  // 64 threads
    if (ei[2 * t + 1] != 0) atomicOr(flag, 1);  // flag=1 -> int32 layout
}

__global__ void repack_kernel(const int* __restrict__ ei, const int* __restrict__ flag,
                              int* __restrict__ row32, int* __restrict__ col32) {
    int e = blockIdx.x * 256 + threadIdx.x;
    if (e >= N_EDGES) return;
    if (*flag == 0) {  // int64 little-endian, values < 2^31
        row32[e] = ei[2 * e];
        col32[e] = ei[2 * (N_EDGES + e)];
    } else {
        row32[e] = ei[e];
        col32[e] = ei[N_EDGES + e];
    }
}

__global__ void count_deg_kernel(const int* __restrict__ col32, int* __restrict__ deg) {
    int e = blockIdx.x * 256 + threadIdx.x;
    if (e < N_EDGES) atomicAdd(&deg[col32[e]], 1);
}

// Single-block scan: 1024 threads x 32 elements. Produces exclusive offsets,
// cursor copy, inv_deg = 1/max(deg,1), and m0 = ones.
__global__ __launch_bounds__(1024) void scan_kernel(
    const int* __restrict__ deg, int* __restrict__ offs, int* __restrict__ cursor,
    float* __restrict__ inv_deg, float* __restrict__ m0) {
    __shared__ int sums[1024];
    int t = threadIdx.x;
    int vals[32];
    int base_idx = t * 32;
    int s = 0;
#pragma unroll
    for (int j = 0; j < 32; j++) { vals[j] = deg[base_idx + j]; s += vals[j]; }
    sums[t] = s;
    __syncthreads();
    for (int off = 1; off < 1024; off <<= 1) {
        int add = 0;
        if (t >= off) add = sums[t - off];
        __syncthreads();
        sums[t] += add;
        __syncthreads();
    }
    int run = (t > 0) ? sums[t - 1] : 0;
#pragma unroll
    for (int j = 0; j < 32; j++) {
        int idx = base_idx + j;
        offs[idx]   = run;
        cursor[idx] = run;
        int d = vals[j];
        inv_deg[idx] = 1.0f / (float)((d > 1) ? d : 1);
        m0[idx] = 1.0f;
        run += d;
    }
    if (t == 1023) offs[N_NODES] = run;
}

__global__ void fill_csr_kernel(const int* __restrict__ row32, const int* __restrict__ col32,
                                int* __restrict__ cursor, int* __restrict__ srcs) {
    int e = blockIdx.x * 256 + threadIdx.x;
    if (e >= N_EDGES) return;
    int c = col32[e];
    int slot = atomicAdd(&cursor[c], 1);
    srcs[slot] = row32[e];
}

// ---------------------------------------------------------------------------
// Weight prep.  gates = softmax(bg/T); u_i = bb_i @ W1_i; c = bo + sum g_i b2_i @ Wo_i
// ---------------------------------------------------------------------------
__global__ __launch_bounds__(128) void prep_misc_kernel(
    const float* __restrict__ bg, const float* __restrict__ temp,
    const float* __restrict__ bb, const float* __restrict__ W1,
    const float* __restrict__ b2, const float* __restrict__ Wo,
    const float* __restrict__ bo,
    float* __restrict__ gates, float* __restrict__ u, float* __restrict__ cvec) {
    __shared__ float g[NB];
    int tid = threadIdx.x;
    if (tid < NB) {
        float T = temp[0];
        float mx = -1e30f;
        for (int q = 0; q < NB; q++) mx = fmaxf(mx, bg[q]);
        float ssum = 0.f;
        for (int q = 0; q < NB; q++) ssum += expf((bg[q] - mx) / T);
        g[tid] = expf((bg[tid] - mx) / T) / ssum;
        gates[tid] = g[tid];
    }
    __syncthreads();
    int f = tid;  // 128 threads, one output feature each
    for (int i = 0; i < NB; i++) {
        float acc = 0.f;
        for (int j = 0; j < OUT_F; j++)
            acc += bb[i * OUT_F + j] * W1[(i * OUT_F + j) * OUT_F + f];
        u[i * OUT_F + f] = acc;
    }
    float cc = bo[f];
    for (int i = 0; i < NB; i++) {
        float t = 0.f;
        for (int j = 0; j < OUT_F; j++)
            t += b2[i * OUT_F + j] * Wo[(i * OUT_F + j) * OUT_F + f];
        cc += g[i] * t;
    }
    cvec[f] = cc;
}

// Wc[i][k][f] = sum_j Wb[i][k][j] * W1[i][j][f]   (one block per (i,k))
__global__ __launch_bounds__(128) void prep_wc_kernel(
    const float* __restrict__ Wb, const float* __restrict__ W1, float* __restrict__ Wc) {
    int b = blockIdx.x;            // 0..1023
    int i = b >> 8, k = b & 255;
    __shared__ float wrow[OUT_F];
    int f = threadIdx.x;
    wrow[f] = Wb[(i * IN_F + k) * OUT_F + f];
    __syncthreads();
    const float* W1i = W1 + i * OUT_F * OUT_F;
    float acc = 0.f;
#pragma unroll 4
    for (int j = 0; j < OUT_F; j++) acc += wrow[j] * W1i[j * OUT_F + f];
    Wc[(i * IN_F + k) * OUT_F + f] = acc;
}

// Wz[i][j][f] = g_i * sum_l W2[i][j][l] * Wo[128i+l][f]   (one block per (i,j))
__global__ __launch_bounds__(128) void prep_wz_kernel(
    const float* __restrict__ W2, const float* __restrict__ Wo,
    const float* __restrict__ gates, float* __restrict__ Wz) {
    int b = blockIdx.x;            // 0..511
    int i = b >> 7, j = b & 127;
    __shared__ float wrow[OUT_F];
    int f = threadIdx.x;
    wrow[f] = W2[(i * OUT_F + j) * OUT_F + f];
    __syncthreads();
    float acc = 0.f;
#pragma unroll 4
    for (int l = 0; l < OUT_F; l++) acc += wrow[l] * Wo[(i * OUT_F + l) * OUT_F + f];
    Wz[(i * OUT_F + j) * OUT_F + f] = gates[i] * acc;
}

// ---------------------------------------------------------------------------
// Propagation: m (scalar per node) and X (256 features, one wave per node)
// ---------------------------------------------------------------------------
__global__ void prop_m_kernel(const float* __restrict__ m_in, float* __restrict__ m_out,
                              const int* __restrict__ offs, const int* __restrict__ srcs,
                              const float* __restrict__ invd) {
    int n = blockIdx.x * 256 + threadIdx.x;
    if (n >= N_NODES) return;
    int s = offs[n], e = offs[n + 1];
    float sum = 0.f;
    for (int p = s; p < e; ++p) sum += m_in[srcs[p]];
    m_out[n] = sum * invd[n];
}

__global__ __launch_bounds__(256) void prop_x_kernel(
    const float* __restrict__ in, float* __restrict__ out,
    const int* __restrict__ offs, const int* __restrict__ srcs,
    const float* __restrict__ invd) {
    int node = blockIdx.x * 4 + (threadIdx.x >> 6);
    int lane = threadIdx.x & 63;
    int s = offs[node], e = offs[node + 1];
    float4 acc = make_float4(0.f, 0.f, 0.f, 0.f);
    for (int p = s; p < e; ++p) {
        int src = srcs[p];
        float4 v = *(const float4*)(in + (size_t)src * IN_F + lane * 4);
        acc.x += v.x; acc.y += v.y; acc.z += v.z; acc.w += v.w;
    }
    float w = invd[node];
    float4 o = make_float4(acc.x * w, acc.y * w, acc.z * w, acc.w * w);
    *(float4*)(out + (size_t)node * IN_F + lane * 4) = o;
}

// ---------------------------------------------------------------------------
// GEMM1: R[:, 128i:128(i+1)] = relu(X_i @ Wc_i + m_i[n]*u_i[f] + b1_i[f])
// 128x128 tile, BK=16, 256 threads, 8x8 per thread, f32 vector FMA.
// ---------------------------------------------------------------------------
__global__ __launch_bounds__(256) void gemm1_kernel(
    const float* __restrict__ A0, const float* __restrict__ A1,
    const float* __restrict__ A2, const float* __restrict__ A3,
    const float* __restrict__ Wc, const float* __restrict__ u,
    const float* __restrict__ b1, const float* __restrict__ m,
    float* __restrict__ R, int branch_base) {
    int branch = branch_base + blockIdx.y;
    const float* A = (branch == 0) ? A0 : (branch == 1) ? A1 : (branch == 2) ? A2 : A3;
    const float* W = Wc + (size_t)branch * IN_F * OUT_F;
    const float* mv = m + (size_t)branch * N_NODES;
    int m0 = blockIdx.x * 128;

    __shared__ __align__(16) float As[16][132];
    __shared__ __align__(16) float Ws[16][128];

    int tid = threadIdx.x;
    int tr = tid >> 4, tc = tid & 15;
    int row0 = tr * 8, col0 = tc * 8;
    float acc[8][8] = {};

    int lr = tid >> 1;
    int lk = (tid & 1) * 4;
    const float* Aload = A + (size_t)(m0 + lr) * IN_F + lk;
    int wkk = tid >> 5;
    int wf = (tid & 31) * 4;

    for (int k0 = 0; k0 < IN_F; k0 += 16) {
        float4 av0 = *(const float4*)(Aload + k0);
        float4 av1 = *(const float4*)(Aload + k0 + 8);
        float4 wv0 = *(const float4*)(W + (size_t)(k0 + wkk) * OUT_F + wf);
        float4 wv1 = *(const float4*)(W + (size_t)(k0 + wkk + 8) * OUT_F + wf);
        __syncthreads();
        As[lk + 0][lr] = av0.x; As[lk + 1][lr] = av0.y;
        As[lk + 2][lr] = av0.z; As[lk + 3][lr] = av0.w;
        As[lk + 8][lr] = av1.x; As[lk + 9][lr] = av1.y;
        As[lk + 10][lr] = av1.z; As[lk + 11][lr] = av1.w;
        *(float4*)&Ws[wkk][wf] = wv0;
        *(float4*)&Ws[wkk + 8][wf] = wv1;
        __syncthreads();
#pragma unroll
        for (int kk = 0; kk < 16; kk++) {
            float a[8], b[8];
            *(float4*)(a)     = *(const float4*)&As[kk][row0];
            *(float4*)(a + 4) = *(const float4*)&As[kk][row0 + 4];
            *(float4*)(b)     = *(const float4*)&Ws[kk][col0];
            *(float4*)(b + 4) = *(const float4*)&Ws[kk][col0 + 4];
#pragma unroll
            for (int r = 0; r < 8; r++)
#pragma unroll
                for (int c = 0; c < 8; c++) acc[r][c] += a[r] * b[c];
        }
    }

    float ub[8], bb1[8];
#pragma unroll
    for (int c = 0; c < 8; c++) {
        ub[c]  = u[branch * OUT_F + col0 + c];
        bb1[c] = b1[branch * OUT_F + col0 + c];
    }
#pragma unroll
    for (int r = 0; r < 8; r++) {
        int rowg = m0 + row0 + r;
        float mval = mv[rowg];
        float o[8];
#pragma unroll
        for (int c = 0; c < 8; c++)
            o[c] = fmaxf(acc[r][c] + mval * ub[c] + bb1[c], 0.f);
        float* dst = R + (size_t)rowg * (NB * OUT_F) + branch * OUT_F + col0;
        *(float4*)(dst)     = *(float4*)(o);
        *(float4*)(dst + 4) = *(float4*)(o + 4);
    }
}

// ---------------------------------------------------------------------------
// GEMM2: out = R[32768,512] @ Wz[512,128] + c
// ---------------------------------------------------------------------------
__global__ __launch_bounds__(256) void gemm2_kernel(
    const float* __restrict__ R, const float* __restrict__ Wz,
    const float* __restrict__ cvec, float* __restrict__ out) {
    int m0 = blockIdx.x * 128;
    __shared__ __align__(16) float As[16][132];
    __shared__ __align__(16) float Ws[16][128];

    int tid = threadIdx.x;
    int tr = tid >> 4, tc = tid & 15;
    int row0 = tr * 8, col0 = tc * 8;
    float acc[8][8] = {};

    int lr = tid >> 1;
    int lk = (tid & 1) * 4;
    const float* Aload = R + (size_t)(m0 + lr) * (NB * OUT_F) + lk;
    int wkk = tid >> 5;
    int wf = (tid & 31) * 4;

    for (int k0 = 0; k0 < NB * OUT_F; k0 += 16) {
        float4 av0 = *(const float4*)(Aload + k0);
        float4 av1 = *(const float4*)(Aload + k0 + 8);
        float4 wv0 = *(const float4*)(Wz + (size_t)(k0 + wkk) * OUT_F + wf);
        float4 wv1 = *(const float4*)(Wz + (size_t)(k0 + wkk + 8) * OUT_F + wf);
        __syncthreads();
        As[lk + 0][lr] = av0.x; As[lk + 1][lr] = av0.y;
        As[lk + 2][lr] = av0.z; As[lk + 3][lr] = av0.w;
        As[lk + 8][lr] = av1.x; As[lk + 9][lr] = av1.y;
        As[lk + 10][lr] = av1.z; As[lk + 11][lr] = av1.w;
        *(float4*)&Ws[wkk][wf] = wv0;
        *(float4*)&Ws[wkk + 8][wf] = wv1;
        __syncthreads();
#pragma unroll
        for (int kk = 0; kk < 16; kk++) {
            float a[8], b[8];
            *(float4*)(a)     = *(const float4*)&As[kk][row0];
            *(float4*)(a + 4) = *(const float4*)&As[kk][row0 + 4];
            *(float4*)(b)     = *(const float4*)&Ws[kk][col0];
            *(float4*)(b + 4) = *(const float4*)&Ws[kk][col0 + 4];
#pragma unroll
            for (int r = 0; r < 8; r++)
#pragma unroll
                for (int c = 0; c < 8; c++) acc[r][c] += a[r] * b[c];
        }
    }

    float cb[8];
#pragma unroll
    for (int c = 0; c < 8; c++) cb[c] = cvec[col0 + c];
#pragma unroll
    for (int r = 0; r < 8; r++) {
        int rowg = m0 + row0 + r;
        float o[8];
#pragma unroll
        for (int c = 0; c < 8; c++) o[c] = acc[r][c] + cb[c];
        float* dst = out + (size_t)rowg * OUT_F + col0;
        *(float4*)(dst)     = *(float4*)(o);
        *(float4*)(dst + 4) = *(float4*)(o + 4);
    }
}

// ---------------------------------------------------------------------------
extern "C" void kernel_launch(void* const* d_in, const int* in_sizes, int n_in,
                              void* d_out, int out_size, void* d_ws, size_t ws_size,
                              hipStream_t stream) {
    const float* x    = (const float*)d_in[0];
    const int*   ei   = (const int*)d_in[1];
    const float* Wb   = (const float*)d_in[2];
    const float* bb   = (const float*)d_in[3];
    const float* W1   = (const float*)d_in[4];
    const float* b1   = (const float*)d_in[5];
    const float* W2   = (const float*)d_in[6];
    const float* b2   = (const float*)d_in[7];
    const float* bg   = (const float*)d_in[8];
    const float* temp = (const float*)d_in[9];
    const float* Wo   = (const float*)d_in[10];
    const float* bo   = (const float*)d_in[11];
    float* out = (float*)d_out;

    // workspace layout (256B-aligned blocks)
    char* w = (char*)d_ws;
    size_t used = 0;
    auto alloc = [&](size_t bytes) {
        char* p = w + used;
        used += (bytes + 255) & ~(size_t)255;
        return p;
    };
    int*   deg    = (int*)alloc(N_NODES * 4);
    int*   flag   = (int*)alloc(4);
    int*   row32  = (int*)alloc(N_EDGES * 4);
    int*   col32  = (int*)alloc(N_EDGES * 4);
    int*   offs   = (int*)alloc((N_NODES + 2) * 4);
    int*   cursor = (int*)alloc(N_NODES * 4);
    int*   srcs   = (int*)alloc(N_EDGES * 4);
    float* invd   = (float*)alloc(N_NODES * 4);
    float* mbuf   = (float*)alloc((size_t)NB * N_NODES * 4);
    float* gates  = (float*)alloc(64 * 4);
    float* u      = (float*)alloc(NB * OUT_F * 4);
    float* cvec   = (float*)alloc(OUT_F * 4);
    float* Wc     = (float*)alloc((size_t)NB * IN_F * OUT_F * 4);
    float* Wz     = (float*)alloc((size_t)NB * OUT_F * OUT_F * 4);
    float* X1     = (float*)alloc((size_t)N_NODES * IN_F * 4);
    float* X2     = (float*)alloc((size_t)N_NODES * IN_F * 4);
    float* R      = (float*)alloc((size_t)N_NODES * NB * OUT_F * 4);
    if (used > ws_size) return;  // ws too small: visible as validation failure

    float* m0v = mbuf;
    float* m1v = mbuf + N_NODES;
    float* m2v = mbuf + 2 * N_NODES;
    float* m3v = mbuf + 3 * N_NODES;

    // 1. zero deg + flag
    hipMemsetAsync(deg, 0, N_NODES * 4, stream);
    hipMemsetAsync(flag, 0, 4, stream);
    // 2. edge dtype detect + repack
    detect_kernel<<<1, 64, 0, stream>>>(ei, flag);
    repack_kernel<<<N_EDGES / 256, 256, 0, stream>>>(ei, flag, row32, col32);
    // 3. degree + CSR
    count_deg_kernel<<<N_EDGES / 256, 256, 0, stream>>>(col32, deg);
    scan_kernel<<<1, 1024, 0, stream>>>(deg, offs, cursor, invd, m0v);
    fill_csr_kernel<<<N_EDGES / 256, 256, 0, stream>>>(row32, col32, cursor, srcs);
    // 4. weight prep
    prep_misc_kernel<<<1, 128, 0, stream>>>(bg, temp, bb, W1, b2, Wo, bo, gates, u, cvec);
    prep_wc_kernel<<<NB * IN_F, 128, 0, stream>>>(Wb, W1, Wc);
    prep_wz_kernel<<<NB * OUT_F, 128, 0, stream>>>(W2, Wo, gates, Wz);
    // 5. bias-propagation vectors m1..m3
    prop_m_kernel<<<N_NODES / 256, 256, 0, stream>>>(m0v, m1v, offs, srcs, invd);
    prop_m_kernel<<<N_NODES / 256, 256, 0, stream>>>(m1v, m2v, offs, srcs, invd);
    prop_m_kernel<<<N_NODES / 256, 256, 0, stream>>>(m2v, m3v, offs, srcs, invd);
    // 6. X propagation (ping-pong) interleaved with GEMM1
    prop_x_kernel<<<N_NODES / 4, 256, 0, stream>>>(x, X1, offs, srcs, invd);
    prop_x_kernel<<<N_NODES / 4, 256, 0, stream>>>(X1, X2, offs, srcs, invd);
    {
        dim3 grid(N_NODES / 128, 3);
        gemm1_kernel<<<grid, 256, 0, stream>>>(x, X1, X2, X2, Wc, u, b1, mbuf, R, 0);
    }
    prop_x_kernel<<<N_NODES / 4, 256, 0, stream>>>(X2, X1, offs, srcs, invd);
    {
        dim3 grid(N_NODES / 128, 1);
        gemm1_kernel<<<grid, 256, 0, stream>>>(x, X1, X2, X1, Wc, u, b1, mbuf, R, 3);
    }
    // 7. final fused GEMM
    gemm2_kernel<<<N_NODES / 128, 256, 0, stream>>>(R, Wz, cvec, out);
}

// Round 2
// 495.183 us; speedup vs baseline: 1.3871x; 1.3871x over previous
//
#include <hip/hip_runtime.h>
#include <math.h>

#define N_NODES 32768
#define N_EDGES 524288
#define IN_F    256
#define OUT_F   128
#define NB      4

typedef __attribute__((ext_vector_type(8))) short bf16x8;
typedef __attribute__((ext_vector_type(4))) float f32x4;

__device__ __forceinline__ ushort f2b(float f) {  // f32 -> bf16 RNE
    uint u = __float_as_uint(f);
    return (ushort)((u + 0x7fffu + ((u >> 16) & 1u)) >> 16);
}
__device__ __forceinline__ float b2f_lo(uint v) { return __uint_as_float(v << 16); }
__device__ __forceinline__ float b2f_hi(uint v) { return __uint_as_float(v & 0xffff0000u); }

// ---------------------------------------------------------------------------
// Edge dtype detection + repack (int64 vs int32 layout, runtime detect)
// ---------------------------------------------------------------------------
__global__ void detect_kernel(const int* __restrict__ ei, int* __restrict__ flag) {
    int t = threadIdx.x;  // 64 threads
    if (ei[2 * t + 1] != 0) atomicOr(flag, 1);  // flag=1 -> int32 layout
}

__global__ void repack_kernel(const int* __restrict__ ei, const int* __restrict__ flag,
                              int* __restrict__ row32, int* __restrict__ col32) {
    int e = blockIdx.x * 256 + threadIdx.x;
    if (e >= N_EDGES) return;
    if (*flag == 0) {
        row32[e] = ei[2 * e];
        col32[e] = ei[2 * (N_EDGES + e)];
    } else {
        row32[e] = ei[e];
        col32[e] = ei[N_EDGES + e];
    }
}

__global__ void count_deg_kernel(const int* __restrict__ col32, int* __restrict__ deg) {
    int e = blockIdx.x * 256 + threadIdx.x;
    if (e < N_EDGES) atomicAdd(&deg[col32[e]], 1);
}

__global__ __launch_bounds__(1024) void scan_kernel(
    const int* __restrict__ deg, int* __restrict__ offs, int* __restrict__ cursor,
    float* __restrict__ inv_deg, float* __restrict__ m0) {
    __shared__ int sums[1024];
    int t = threadIdx.x;
    int vals[32];
    int base_idx = t * 32;
    int s = 0;
#pragma unroll
    for (int j = 0; j < 32; j++) { vals[j] = deg[base_idx + j]; s += vals[j]; }
    sums[t] = s;
    __syncthreads();
    for (int off = 1; off < 1024; off <<= 1) {
        int add = 0;
        if (t >= off) add = sums[t - off];
        __syncthreads();
        sums[t] += add;
        __syncthreads();
    }
    int run = (t > 0) ? sums[t - 1] : 0;
#pragma unroll
    for (int j = 0; j < 32; j++) {
        int idx = base_idx + j;
        offs[idx]   = run;
        cursor[idx] = run;
        int d = vals[j];
        inv_deg[idx] = 1.0f / (float)((d > 1) ? d : 1);
        m0[idx] = 1.0f;
        run += d;
    }
    if (t == 1023) offs[N_NODES] = run;
}

__global__ void fill_csr_kernel(const int* __restrict__ row32, const int* __restrict__ col32,
                                int* __restrict__ cursor, int* __restrict__ srcs) {
    int e = blockIdx.x * 256 + threadIdx.x;
    if (e >= N_EDGES) return;
    int c = col32[e];
    int slot = atomicAdd(&cursor[c], 1);
    srcs[slot] = row32[e];
}

// ---------------------------------------------------------------------------
// Weight prep
// ---------------------------------------------------------------------------
__global__ __launch_bounds__(128) void prep_misc_kernel(
    const float* __restrict__ bg, const float* __restrict__ temp,
    const float* __restrict__ bb, const float* __restrict__ W1,
    const float* __restrict__ b2, const float* __restrict__ Wo,
    const float* __restrict__ bo,
    float* __restrict__ gates, float* __restrict__ u, float* __restrict__ cvec) {
    __shared__ float g[NB];
    int tid = threadIdx.x;
    if (tid < NB) {
        float T = temp[0];
        float mx = -1e30f;
        for (int q = 0; q < NB; q++) mx = fmaxf(mx, bg[q]);
        float ssum = 0.f;
        for (int q = 0; q < NB; q++) ssum += expf((bg[q] - mx) / T);
        g[tid] = expf((bg[tid] - mx) / T) / ssum;
        gates[tid] = g[tid];
    }
    __syncthreads();
    int f = tid;
    for (int i = 0; i < NB; i++) {
        float acc = 0.f;
        for (int j = 0; j < OUT_F; j++)
            acc += bb[i * OUT_F + j] * W1[(i * OUT_F + j) * OUT_F + f];
        u[i * OUT_F + f] = acc;
    }
    float cc = bo[f];
    for (int i = 0; i < NB; i++) {
        float t = 0.f;
        for (int j = 0; j < OUT_F; j++)
            t += b2[i * OUT_F + j] * Wo[(i * OUT_F + j) * OUT_F + f];
        cc += g[i] * t;
    }
    cvec[f] = cc;
}

// WcT[i][f][k] = sum_j Wb[i][k][j] * W1[i][j][f]  (bf16, transposed for MFMA B)
__global__ __launch_bounds__(128) void prep_wc_kernel(
    const float* __restrict__ Wb, const float* __restrict__ W1, ushort* __restrict__ WcT) {
    int b = blockIdx.x;            // 0..1023
    int i = b >> 8, k = b & 255;
    __shared__ float wrow[OUT_F];
    int f = threadIdx.x;
    wrow[f] = Wb[(i * IN_F + k) * OUT_F + f];
    __syncthreads();
    const float* W1i = W1 + i * OUT_F * OUT_F;
    float acc = 0.f;
#pragma unroll 4
    for (int j = 0; j < OUT_F; j++) acc += wrow[j] * W1i[j * OUT_F + f];
    WcT[(size_t)(i * OUT_F + f) * IN_F + k] = f2b(acc);
}

// WzT[f][i*128+j] = g_i * sum_l W2[i][j][l] * Wo[128i+l][f]  (bf16 transposed)
__global__ __launch_bounds__(128) void prep_wz_kernel(
    const float* __restrict__ W2, const float* __restrict__ Wo,
    const float* __restrict__ gates, ushort* __restrict__ WzT) {
    int b = blockIdx.x;            // 0..511
    int i = b >> 7, j = b & 127;
    __shared__ float wrow[OUT_F];
    int f = threadIdx.x;
    wrow[f] = W2[(i * OUT_F + j) * OUT_F + f];
    __syncthreads();
    float acc = 0.f;
#pragma unroll 4
    for (int l = 0; l < OUT_F; l++) acc += wrow[l] * Wo[(i * OUT_F + l) * OUT_F + f];
    WzT[(size_t)f * (NB * OUT_F) + i * OUT_F + j] = f2b(gates[i] * acc);
}

// x (f32) -> xb (bf16)
__global__ __launch_bounds__(256) void convert_bf16_kernel(
    const float* __restrict__ x, ushort* __restrict__ xb) {
    int idx = blockIdx.x * 256 + threadIdx.x;  // 4 floats each
    float4 v = ((const float4*)x)[idx];
    ushort4 o;
    o.x = f2b(v.x); o.y = f2b(v.y); o.z = f2b(v.z); o.w = f2b(v.w);
    ((ushort4*)xb)[idx] = o;
}

// ---------------------------------------------------------------------------
// Propagation
// ---------------------------------------------------------------------------
__global__ void prop_m_kernel(const float* __restrict__ m_in, float* __restrict__ m_out,
                              const int* __restrict__ offs, const int* __restrict__ srcs,
                              const float* __restrict__ invd) {
    int n = blockIdx.x * 256 + threadIdx.x;
    if (n >= N_NODES) return;
    int s = offs[n], e = offs[n + 1];
    float sum = 0.f;
    for (int p = s; p < e; ++p) sum += m_in[srcs[p]];
    m_out[n] = sum * invd[n];
}

// one wave per node; lane covers 4 bf16 features (8B per edge-row)
__global__ __launch_bounds__(256) void prop_x_bf16_kernel(
    const ushort* __restrict__ in, ushort* __restrict__ out,
    const int* __restrict__ offs, const int* __restrict__ srcs,
    const float* __restrict__ invd) {
    int node = blockIdx.x * 4 + (threadIdx.x >> 6);
    int lane = threadIdx.x & 63;
    int s = offs[node], e = offs[node + 1];
    float a0 = 0.f, a1 = 0.f, a2 = 0.f, a3 = 0.f;
    for (int p = s; p < e; ++p) {
        int src = srcs[p];
        uint2 v = *(const uint2*)(in + (size_t)src * IN_F + lane * 4);
        a0 += b2f_lo(v.x); a1 += b2f_hi(v.x);
        a2 += b2f_lo(v.y); a3 += b2f_hi(v.y);
    }
    float w = invd[node];
    ushort4 o;
    o.x = f2b(a0 * w); o.y = f2b(a1 * w); o.z = f2b(a2 * w); o.w = f2b(a3 * w);
    *(ushort4*)(out + (size_t)node * IN_F + lane * 4) = o;
}

// ---------------------------------------------------------------------------
// GEMM1 (MFMA): R[:,128b:128b+128] = relu(X_b @ Wc_b + m_b*u_b + b1_b), bf16 out
// 128x128 tile, K=256 in 4 chunks of 64, 4 waves, 16x16x32 bf16 MFMA
// ---------------------------------------------------------------------------
__global__ __launch_bounds__(256) void gemm1_mfma_kernel(
    const ushort* __restrict__ A0, const ushort* __restrict__ A1,
    const ushort* __restrict__ A2, const ushort* __restrict__ A3,
    const ushort* __restrict__ WcT, const float* __restrict__ u,
    const float* __restrict__ b1, const float* __restrict__ m,
    ushort* __restrict__ R) {
    int branch = blockIdx.y;
    const ushort* A = (branch == 0) ? A0 : (branch == 1) ? A1 : (branch == 2) ? A2 : A3;
    const ushort* WT = WcT + (size_t)branch * OUT_F * IN_F;
    const float* mv = m + (size_t)branch * N_NODES;
    int m0 = blockIdx.x * 128;

    __shared__ ushort As[128][72];   // +8 pad: bank-balanced b128 reads
    __shared__ ushort Bs[128][72];

    int tid = threadIdx.x;
    int wv = tid >> 6, lane = tid & 63, quad = lane >> 4, lm = lane & 15;

    f32x4 acc[2][8];
    f32x4 zero = {0.f, 0.f, 0.f, 0.f};
#pragma unroll
    for (int i = 0; i < 2; i++)
#pragma unroll
        for (int j = 0; j < 8; j++) acc[i][j] = zero;

    for (int k0 = 0; k0 < IN_F; k0 += 64) {
        __syncthreads();
#pragma unroll
        for (int it = 0; it < 4; it++) {
            int c = tid + 256 * it;      // 0..1023 chunks of 16B
            int r = c >> 3, c8 = c & 7;
            *(uint4*)&As[r][c8 * 8] = *(const uint4*)(A + (size_t)(m0 + r) * IN_F + k0 + c8 * 8);
            *(uint4*)&Bs[r][c8 * 8] = *(const uint4*)(WT + (size_t)r * IN_F + k0 + c8 * 8);
        }
        __syncthreads();
#pragma unroll
        for (int ks = 0; ks < 2; ks++) {
            bf16x8 af0 = *(const bf16x8*)&As[wv * 32 + lm][ks * 32 + quad * 8];
            bf16x8 af1 = *(const bf16x8*)&As[wv * 32 + 16 + lm][ks * 32 + quad * 8];
#pragma unroll
            for (int nt = 0; nt < 8; nt++) {
                bf16x8 bf = *(const bf16x8*)&Bs[nt * 16 + lm][ks * 32 + quad * 8];
                acc[0][nt] = __builtin_amdgcn_mfma_f32_16x16x32_bf16(af0, bf, acc[0][nt], 0, 0, 0);
                acc[1][nt] = __builtin_amdgcn_mfma_f32_16x16x32_bf16(af1, bf, acc[1][nt], 0, 0, 0);
            }
        }
    }

    float uv[8], bv[8];
#pragma unroll
    for (int nt = 0; nt < 8; nt++) {
        int col = nt * 16 + lm;
        uv[nt] = u[branch * OUT_F + col];
        bv[nt] = b1[branch * OUT_F + col];
    }
#pragma unroll
    for (int mt = 0; mt < 2; mt++)
#pragma unroll
        for (int r = 0; r < 4; r++) {
            int row = m0 + wv * 32 + mt * 16 + quad * 4 + r;
            float mval = mv[row];
#pragma unroll
            for (int nt = 0; nt < 8; nt++) {
                int col = nt * 16 + lm;
                float h = acc[mt][nt][r] + mval * uv[nt] + bv[nt];
                R[(size_t)row * (NB * OUT_F) + branch * OUT_F + col] = f2b(fmaxf(h, 0.f));
            }
        }
}

// ---------------------------------------------------------------------------
// GEMM2 (MFMA): out = R[32768,512](bf16) @ Wz(bf16) + c  -> f32
// ---------------------------------------------------------------------------
__global__ __launch_bounds__(256) void gemm2_mfma_kernel(
    const ushort* __restrict__ R, const ushort* __restrict__ WzT,
    const float* __restrict__ cvec, float* __restrict__ out) {
    int m0 = blockIdx.x * 128;
    const int K = NB * OUT_F;  // 512

    __shared__ ushort As[128][72];
    __shared__ ushort Bs[128][72];

    int tid = threadIdx.x;
    int wv = tid >> 6, lane = tid & 63, quad = lane >> 4, lm = lane & 15;

    f32x4 acc[2][8];
    f32x4 zero = {0.f, 0.f, 0.f, 0.f};
#pragma unroll
    for (int i = 0; i < 2; i++)
#pragma unroll
        for (int j = 0; j < 8; j++) acc[i][j] = zero;

    for (int k0 = 0; k0 < K; k0 += 64) {
        __syncthreads();
#pragma unroll
        for (int it = 0; it < 4; it++) {
            int c = tid + 256 * it;
            int r = c >> 3, c8 = c & 7;
            *(uint4*)&As[r][c8 * 8] = *(const uint4*)(R + (size_t)(m0 + r) * K + k0 + c8 * 8);
            *(uint4*)&Bs[r][c8 * 8] = *(const uint4*)(WzT + (size_t)r * K + k0 + c8 * 8);
        }
        __syncthreads();
#pragma unroll
        for (int ks = 0; ks < 2; ks++) {
            bf16x8 af0 = *(const bf16x8*)&As[wv * 32 + lm][ks * 32 + quad * 8];
            bf16x8 af1 = *(const bf16x8*)&As[wv * 32 + 16 + lm][ks * 32 + quad * 8];
#pragma unroll
            for (int nt = 0; nt < 8; nt++) {
                bf16x8 bf = *(const bf16x8*)&Bs[nt * 16 + lm][ks * 32 + quad * 8];
                acc[0][nt] = __builtin_amdgcn_mfma_f32_16x16x32_bf16(af0, bf, acc[0][nt], 0, 0, 0);
                acc[1][nt] = __builtin_amdgcn_mfma_f32_16x16x32_bf16(af1, bf, acc[1][nt], 0, 0, 0);
            }
        }
    }

    float cb[8];
#pragma unroll
    for (int nt = 0; nt < 8; nt++) cb[nt] = cvec[nt * 16 + lm];
#pragma unroll
    for (int mt = 0; mt < 2; mt++)
#pragma unroll
        for (int r = 0; r < 4; r++) {
            int row = m0 + wv * 32 + mt * 16 + quad * 4 + r;
#pragma unroll
            for (int nt = 0; nt < 8; nt++) {
                int col = nt * 16 + lm;
                out[(size_t)row * OUT_F + col] = acc[mt][nt][r] + cb[nt];
            }
        }
}

// ---------------------------------------------------------------------------
extern "C" void kernel_launch(void* const* d_in, const int* in_sizes, int n_in,
                              void* d_out, int out_size, void* d_ws, size_t ws_size,
                              hipStream_t stream) {
    const float* x    = (const float*)d_in[0];
    const int*   ei   = (const int*)d_in[1];
    const float* Wb   = (const float*)d_in[2];
    const float* bb   = (const float*)d_in[3];
    const float* W1   = (const float*)d_in[4];
    const float* b1   = (const float*)d_in[5];
    const float* W2   = (const float*)d_in[6];
    const float* b2   = (const float*)d_in[7];
    const float* bg   = (const float*)d_in[8];
    const float* temp = (const float*)d_in[9];
    const float* Wo   = (const float*)d_in[10];
    const float* bo   = (const float*)d_in[11];
    float* out = (float*)d_out;

    char* w = (char*)d_ws;
    size_t used = 0;
    auto alloc = [&](size_t bytes) {
        char* p = w + used;
        used += (bytes + 255) & ~(size_t)255;
        return p;
    };
    int*    deg    = (int*)alloc(N_NODES * 4);
    int*    flag   = (int*)alloc(4);
    int*    row32  = (int*)alloc(N_EDGES * 4);
    int*    col32  = (int*)alloc(N_EDGES * 4);
    int*    offs   = (int*)alloc((N_NODES + 2) * 4);
    int*    cursor = (int*)alloc(N_NODES * 4);
    int*    srcs   = (int*)alloc(N_EDGES * 4);
    float*  invd   = (float*)alloc(N_NODES * 4);
    float*  mbuf   = (float*)alloc((size_t)NB * N_NODES * 4);
    float*  gates  = (float*)alloc(64 * 4);
    float*  u      = (float*)alloc(NB * OUT_F * 4);
    float*  cvec   = (float*)alloc(OUT_F * 4);
    ushort* WcT    = (ushort*)alloc((size_t)NB * IN_F * OUT_F * 2);
    ushort* WzT    = (ushort*)alloc((size_t)NB * OUT_F * OUT_F * 2);
    ushort* xb     = (ushort*)alloc((size_t)N_NODES * IN_F * 2);
    ushort* X1b    = (ushort*)alloc((size_t)N_NODES * IN_F * 2);
    ushort* X2b    = (ushort*)alloc((size_t)N_NODES * IN_F * 2);
    ushort* X3b    = (ushort*)alloc((size_t)N_NODES * IN_F * 2);
    ushort* R      = (ushort*)alloc((size_t)N_NODES * NB * OUT_F * 2);
    if (used > ws_size) return;

    float* m0v = mbuf;
    float* m1v = mbuf + N_NODES;
    float* m2v = mbuf + 2 * N_NODES;
    float* m3v = mbuf + 3 * N_NODES;

    hipMemsetAsync(deg, 0, N_NODES * 4, stream);
    hipMemsetAsync(flag, 0, 4, stream);

    detect_kernel<<<1, 64, 0, stream>>>(ei, flag);
    repack_kernel<<<N_EDGES / 256, 256, 0, stream>>>(ei, flag, row32, col32);
    count_deg_kernel<<<N_EDGES / 256, 256, 0, stream>>>(col32, deg);
    scan_kernel<<<1, 1024, 0, stream>>>(deg, offs, cursor, invd, m0v);
    fill_csr_kernel<<<N_EDGES / 256, 256, 0, stream>>>(row32, col32, cursor, srcs);

    prep_misc_kernel<<<1, 128, 0, stream>>>(bg, temp, bb, W1, b2, Wo, bo, gates, u, cvec);
    prep_wc_kernel<<<NB * IN_F, 128, 0, stream>>>(Wb, W1, WcT);
    prep_wz_kernel<<<NB * OUT_F, 128, 0, stream>>>(W2, Wo, gates, WzT);
    convert_bf16_kernel<<<(N_NODES * IN_F / 4) / 256, 256, 0, stream>>>(x, xb);

    prop_m_kernel<<<N_NODES / 256, 256, 0, stream>>>(m0v, m1v, offs, srcs, invd);
    prop_m_kernel<<<N_NODES / 256, 256, 0, stream>>>(m1v, m2v, offs, srcs, invd);
    prop_m_kernel<<<N_NODES / 256, 256, 0, stream>>>(m2v, m3v, offs, srcs, invd);

    prop_x_bf16_kernel<<<N_NODES / 4, 256, 0, stream>>>(xb, X1b, offs, srcs, invd);
    prop_x_bf16_kernel<<<N_NODES / 4, 256, 0, stream>>>(X1b, X2b, offs, srcs, invd);
    prop_x_bf16_kernel<<<N_NODES / 4, 256, 0, stream>>>(X2b, X3b, offs, srcs, invd);

    {
        dim3 grid(N_NODES / 128, NB);
        gemm1_mfma_kernel<<<grid, 256, 0, stream>>>(xb, X1b, X2b, X3b, WcT, u, b1, mbuf, R);
    }
    gemm2_mfma_kernel<<<N_NODES / 128, 256, 0, stream>>>(R, WzT, cvec, out);
}

// Round 3
// 418.034 us; speedup vs baseline: 1.6431x; 1.1846x over previous
//
#include <hip/hip_runtime.h>
#include <math.h>

#define N_NODES 32768
#define N_EDGES 524288
#define IN_F    256
#define OUT_F   128
#define NB      4

typedef __attribute__((ext_vector_type(8))) short bf16x8;
typedef __attribute__((ext_vector_type(4))) float f32x4;

__device__ __forceinline__ ushort f2b(float f) {  // f32 -> bf16 RNE
    uint u = __float_as_uint(f);
    return (ushort)((u + 0x7fffu + ((u >> 16) & 1u)) >> 16);
}
__device__ __forceinline__ float b2f_lo(uint v) { return __uint_as_float(v << 16); }
__device__ __forceinline__ float b2f_hi(uint v) { return __uint_as_float(v & 0xffff0000u); }

// ---------------------------------------------------------------------------
// Edge dtype detection + repack+degree-count (int64 vs int32 layout)
// ---------------------------------------------------------------------------
__global__ void detect_kernel(const int* __restrict__ ei, int* __restrict__ flag) {
    int t = threadIdx.x;  // 64 threads
    if (ei[2 * t + 1] != 0) atomicOr(flag, 1);  // flag=1 -> int32 layout
}

__global__ void repack_count_kernel(const int* __restrict__ ei, const int* __restrict__ flag,
                                    int* __restrict__ row32, int* __restrict__ col32,
                                    int* __restrict__ deg) {
    int e = blockIdx.x * 256 + threadIdx.x;
    if (e >= N_EDGES) return;
    int r, c;
    if (*flag == 0) {
        r = ei[2 * e];
        c = ei[2 * (N_EDGES + e)];
    } else {
        r = ei[e];
        c = ei[N_EDGES + e];
    }
    row32[e] = r;
    col32[e] = c;
    atomicAdd(&deg[c], 1);
}

__global__ __launch_bounds__(1024) void scan_kernel(
    const int* __restrict__ deg, int* __restrict__ offs, int* __restrict__ cursor,
    float* __restrict__ inv_deg, float* __restrict__ m0) {
    __shared__ int sums[1024];
    int t = threadIdx.x;
    int vals[32];
    int base_idx = t * 32;
    int s = 0;
#pragma unroll
    for (int j = 0; j < 32; j++) { vals[j] = deg[base_idx + j]; s += vals[j]; }
    sums[t] = s;
    __syncthreads();
    for (int off = 1; off < 1024; off <<= 1) {
        int add = 0;
        if (t >= off) add = sums[t - off];
        __syncthreads();
        sums[t] += add;
        __syncthreads();
    }
    int run = (t > 0) ? sums[t - 1] : 0;
#pragma unroll
    for (int j = 0; j < 32; j++) {
        int idx = base_idx + j;
        offs[idx]   = run;
        cursor[idx] = run;
        int d = vals[j];
        inv_deg[idx] = 1.0f / (float)((d > 1) ? d : 1);
        m0[idx] = 1.0f;
        run += d;
    }
    if (t == 1023) offs[N_NODES] = run;
}

__global__ void fill_csr_kernel(const int* __restrict__ row32, const int* __restrict__ col32,
                                int* __restrict__ cursor, int* __restrict__ srcs) {
    int e = blockIdx.x * 256 + threadIdx.x;
    if (e >= N_EDGES) return;
    int c = col32[e];
    int slot = atomicAdd(&cursor[c], 1);
    srcs[slot] = row32[e];
}

// ---------------------------------------------------------------------------
// Weight prep
// ---------------------------------------------------------------------------
__global__ __launch_bounds__(128) void prep_misc_kernel(
    const float* __restrict__ bg, const float* __restrict__ temp,
    const float* __restrict__ bb, const float* __restrict__ W1,
    const float* __restrict__ b2, const float* __restrict__ Wo,
    const float* __restrict__ bo,
    float* __restrict__ gates, float* __restrict__ u, float* __restrict__ cvec) {
    __shared__ float g[NB];
    int tid = threadIdx.x;
    if (tid < NB) {
        float T = temp[0];
        float mx = -1e30f;
        for (int q = 0; q < NB; q++) mx = fmaxf(mx, bg[q]);
        float ssum = 0.f;
        for (int q = 0; q < NB; q++) ssum += expf((bg[q] - mx) / T);
        g[tid] = expf((bg[tid] - mx) / T) / ssum;
        gates[tid] = g[tid];
    }
    __syncthreads();
    int f = tid;
    for (int i = 0; i < NB; i++) {
        float acc = 0.f;
        for (int j = 0; j < OUT_F; j++)
            acc += bb[i * OUT_F + j] * W1[(i * OUT_F + j) * OUT_F + f];
        u[i * OUT_F + f] = acc;
    }
    float cc = bo[f];
    for (int i = 0; i < NB; i++) {
        float t = 0.f;
        for (int j = 0; j < OUT_F; j++)
            t += b2[i * OUT_F + j] * Wo[(i * OUT_F + j) * OUT_F + f];
        cc += g[i] * t;
    }
    cvec[f] = cc;
}

// WcT[i][f][k] = sum_j Wb[i][k][j] * W1[i][j][f]  (bf16, transposed for MFMA B)
__global__ __launch_bounds__(128) void prep_wc_kernel(
    const float* __restrict__ Wb, const float* __restrict__ W1, ushort* __restrict__ WcT) {
    int b = blockIdx.x;            // 0..1023
    int i = b >> 8, k = b & 255;
    __shared__ float wrow[OUT_F];
    int f = threadIdx.x;
    wrow[f] = Wb[(i * IN_F + k) * OUT_F + f];
    __syncthreads();
    const float* W1i = W1 + i * OUT_F * OUT_F;
    float acc = 0.f;
#pragma unroll 4
    for (int j = 0; j < OUT_F; j++) acc += wrow[j] * W1i[j * OUT_F + f];
    WcT[(size_t)(i * OUT_F + f) * IN_F + k] = f2b(acc);
}

// WzT[f][i*128+j] = g_i * sum_l W2[i][j][l] * Wo[128i+l][f]  (bf16 transposed)
__global__ __launch_bounds__(128) void prep_wz_kernel(
    const float* __restrict__ W2, const float* __restrict__ Wo,
    const float* __restrict__ gates, ushort* __restrict__ WzT) {
    int b = blockIdx.x;            // 0..511
    int i = b >> 7, j = b & 127;
    __shared__ float wrow[OUT_F];
    int f = threadIdx.x;
    wrow[f] = W2[(i * OUT_F + j) * OUT_F + f];
    __syncthreads();
    float acc = 0.f;
#pragma unroll 4
    for (int l = 0; l < OUT_F; l++) acc += wrow[l] * Wo[(i * OUT_F + l) * OUT_F + f];
    WzT[(size_t)f * (NB * OUT_F) + i * OUT_F + j] = f2b(gates[i] * acc);
}

// x (f32) -> xb (bf16)
__global__ __launch_bounds__(256) void convert_bf16_kernel(
    const float* __restrict__ x, ushort* __restrict__ xb) {
    int idx = blockIdx.x * 256 + threadIdx.x;  // 4 floats each
    float4 v = ((const float4*)x)[idx];
    ushort4 o;
    o.x = f2b(v.x); o.y = f2b(v.y); o.z = f2b(v.z); o.w = f2b(v.w);
    ((ushort4*)xb)[idx] = o;
}

// ---------------------------------------------------------------------------
// Propagation
// ---------------------------------------------------------------------------
__global__ void prop_m_kernel(const float* __restrict__ m_in, float* __restrict__ m_out,
                              const int* __restrict__ offs, const int* __restrict__ srcs,
                              const float* __restrict__ invd) {
    int n = blockIdx.x * 256 + threadIdx.x;
    if (n >= N_NODES) return;
    int s = offs[n], e = offs[n + 1];
    float sum = 0.f;
    for (int p = s; p < e; ++p) sum += m_in[srcs[p]];
    m_out[n] = sum * invd[n];
}

// one wave per node; 32 lanes span the 256-feat row (16B = 8 bf16 per lane);
// two half-waves process two edges per iteration, unrolled x2 => 4 loads in
// flight per wave per iteration. Cross-half shfl reduce at the end.
__global__ __launch_bounds__(256) void prop_x_bf16_kernel(
    const ushort* __restrict__ in, ushort* __restrict__ out,
    const int* __restrict__ offs, const int* __restrict__ srcs,
    const float* __restrict__ invd) {
    int node = blockIdx.x * 4 + (threadIdx.x >> 6);
    int lane = threadIdx.x & 63;
    int half = lane >> 5;      // which edge of the pair
    int fl   = lane & 31;      // 16-byte feature chunk
    int s = offs[node], e = offs[node + 1];

    float a0[8] = {0.f, 0.f, 0.f, 0.f, 0.f, 0.f, 0.f, 0.f};
    float a1[8] = {0.f, 0.f, 0.f, 0.f, 0.f, 0.f, 0.f, 0.f};

    int p = s;
    for (; p + 4 <= e; p += 4) {
        // half 0 -> edges p, p+1 ; half 1 -> edges p+2, p+3 (uint2 srcs load)
        int2 ss = *(const int2*)(srcs + p + 2 * half);
        uint4 v0 = *(const uint4*)(in + (size_t)ss.x * IN_F + fl * 8);
        uint4 v1 = *(const uint4*)(in + (size_t)ss.y * IN_F + fl * 8);
        a0[0] += b2f_lo(v0.x); a0[1] += b2f_hi(v0.x);
        a0[2] += b2f_lo(v0.y); a0[3] += b2f_hi(v0.y);
        a0[4] += b2f_lo(v0.z); a0[5] += b2f_hi(v0.z);
        a0[6] += b2f_lo(v0.w); a0[7] += b2f_hi(v0.w);
        a1[0] += b2f_lo(v1.x); a1[1] += b2f_hi(v1.x);
        a1[2] += b2f_lo(v1.y); a1[3] += b2f_hi(v1.y);
        a1[4] += b2f_lo(v1.z); a1[5] += b2f_hi(v1.z);
        a1[6] += b2f_lo(v1.w); a1[7] += b2f_hi(v1.w);
    }
    // remainder (0..3 edges): half 0 -> edge p, half 1 -> edge p+1
    for (; p + half < e; p += 2) {
        int src = srcs[p + half];
        uint4 v0 = *(const uint4*)(in + (size_t)src * IN_F + fl * 8);
        a0[0] += b2f_lo(v0.x); a0[1] += b2f_hi(v0.x);
        a0[2] += b2f_lo(v0.y); a0[3] += b2f_hi(v0.y);
        a0[4] += b2f_lo(v0.z); a0[5] += b2f_hi(v0.z);
        a0[6] += b2f_lo(v0.w); a0[7] += b2f_hi(v0.w);
    }
#pragma unroll
    for (int k = 0; k < 8; k++) a0[k] += a1[k];
#pragma unroll
    for (int k = 0; k < 8; k++) a0[k] += __shfl_down(a0[k], 32);

    if (half == 0) {
        float w = invd[node];
        uint4 o;
        o.x = (uint)f2b(a0[0] * w) | ((uint)f2b(a0[1] * w) << 16);
        o.y = (uint)f2b(a0[2] * w) | ((uint)f2b(a0[3] * w) << 16);
        o.z = (uint)f2b(a0[4] * w) | ((uint)f2b(a0[5] * w) << 16);
        o.w = (uint)f2b(a0[6] * w) | ((uint)f2b(a0[7] * w) << 16);
        *(uint4*)(out + (size_t)node * IN_F + fl * 8) = o;
    }
}

// ---------------------------------------------------------------------------
// GEMM1 (MFMA): R[:,128b:128b+128] = relu(X_b @ Wc_b + m_b*u_b + b1_b), bf16 out
// ---------------------------------------------------------------------------
__global__ __launch_bounds__(256) void gemm1_mfma_kernel(
    const ushort* __restrict__ A0, const ushort* __restrict__ A1,
    const ushort* __restrict__ A2, const ushort* __restrict__ A3,
    const ushort* __restrict__ WcT, const float* __restrict__ u,
    const float* __restrict__ b1, const float* __restrict__ m,
    ushort* __restrict__ R) {
    int branch = blockIdx.y;
    const ushort* A = (branch == 0) ? A0 : (branch == 1) ? A1 : (branch == 2) ? A2 : A3;
    const ushort* WT = WcT + (size_t)branch * OUT_F * IN_F;
    const float* mv = m + (size_t)branch * N_NODES;
    int m0 = blockIdx.x * 128;

    __shared__ ushort As[128][72];
    __shared__ ushort Bs[128][72];

    int tid = threadIdx.x;
    int wv = tid >> 6, lane = tid & 63, quad = lane >> 4, lm = lane & 15;

    f32x4 acc[2][8];
    f32x4 zero = {0.f, 0.f, 0.f, 0.f};
#pragma unroll
    for (int i = 0; i < 2; i++)
#pragma unroll
        for (int j = 0; j < 8; j++) acc[i][j] = zero;

    for (int k0 = 0; k0 < IN_F; k0 += 64) {
        __syncthreads();
#pragma unroll
        for (int it = 0; it < 4; it++) {
            int c = tid + 256 * it;
            int r = c >> 3, c8 = c & 7;
            *(uint4*)&As[r][c8 * 8] = *(const uint4*)(A + (size_t)(m0 + r) * IN_F + k0 + c8 * 8);
            *(uint4*)&Bs[r][c8 * 8] = *(const uint4*)(WT + (size_t)r * IN_F + k0 + c8 * 8);
        }
        __syncthreads();
#pragma unroll
        for (int ks = 0; ks < 2; ks++) {
            bf16x8 af0 = *(const bf16x8*)&As[wv * 32 + lm][ks * 32 + quad * 8];
            bf16x8 af1 = *(const bf16x8*)&As[wv * 32 + 16 + lm][ks * 32 + quad * 8];
#pragma unroll
            for (int nt = 0; nt < 8; nt++) {
                bf16x8 bf = *(const bf16x8*)&Bs[nt * 16 + lm][ks * 32 + quad * 8];
                acc[0][nt] = __builtin_amdgcn_mfma_f32_16x16x32_bf16(af0, bf, acc[0][nt], 0, 0, 0);
                acc[1][nt] = __builtin_amdgcn_mfma_f32_16x16x32_bf16(af1, bf, acc[1][nt], 0, 0, 0);
            }
        }
    }

    float uv[8], bv[8];
#pragma unroll
    for (int nt = 0; nt < 8; nt++) {
        int col = nt * 16 + lm;
        uv[nt] = u[branch * OUT_F + col];
        bv[nt] = b1[branch * OUT_F + col];
    }
#pragma unroll
    for (int mt = 0; mt < 2; mt++)
#pragma unroll
        for (int r = 0; r < 4; r++) {
            int row = m0 + wv * 32 + mt * 16 + quad * 4 + r;
            float mval = mv[row];
#pragma unroll
            for (int nt = 0; nt < 8; nt++) {
                int col = nt * 16 + lm;
                float h = acc[mt][nt][r] + mval * uv[nt] + bv[nt];
                R[(size_t)row * (NB * OUT_F) + branch * OUT_F + col] = f2b(fmaxf(h, 0.f));
            }
        }
}

// ---------------------------------------------------------------------------
// GEMM2 (MFMA): out = R[32768,512](bf16) @ Wz(bf16) + c  -> f32
// ---------------------------------------------------------------------------
__global__ __launch_bounds__(256) void gemm2_mfma_kernel(
    const ushort* __restrict__ R, const ushort* __restrict__ WzT,
    const float* __restrict__ cvec, float* __restrict__ out) {
    int m0 = blockIdx.x * 128;
    const int K = NB * OUT_F;  // 512

    __shared__ ushort As[128][72];
    __shared__ ushort Bs[128][72];

    int tid = threadIdx.x;
    int wv = tid >> 6, lane = tid & 63, quad = lane >> 4, lm = lane & 15;

    f32x4 acc[2][8];
    f32x4 zero = {0.f, 0.f, 0.f, 0.f};
#pragma unroll
    for (int i = 0; i < 2; i++)
#pragma unroll
        for (int j = 0; j < 8; j++) acc[i][j] = zero;

    for (int k0 = 0; k0 < K; k0 += 64) {
        __syncthreads();
#pragma unroll
        for (int it = 0; it < 4; it++) {
            int c = tid + 256 * it;
            int r = c >> 3, c8 = c & 7;
            *(uint4*)&As[r][c8 * 8] = *(const uint4*)(R + (size_t)(m0 + r) * K + k0 + c8 * 8);
            *(uint4*)&Bs[r][c8 * 8] = *(const uint4*)(WzT + (size_t)r * K + k0 + c8 * 8);
        }
        __syncthreads();
#pragma unroll
        for (int ks = 0; ks < 2; ks++) {
            bf16x8 af0 = *(const bf16x8*)&As[wv * 32 + lm][ks * 32 + quad * 8];
            bf16x8 af1 = *(const bf16x8*)&As[wv * 32 + 16 + lm][ks * 32 + quad * 8];
#pragma unroll
            for (int nt = 0; nt < 8; nt++) {
                bf16x8 bf = *(const bf16x8*)&Bs[nt * 16 + lm][ks * 32 + quad * 8];
                acc[0][nt] = __builtin_amdgcn_mfma_f32_16x16x32_bf16(af0, bf, acc[0][nt], 0, 0, 0);
                acc[1][nt] = __builtin_amdgcn_mfma_f32_16x16x32_bf16(af1, bf, acc[1][nt], 0, 0, 0);
            }
        }
    }

    float cb[8];
#pragma unroll
    for (int nt = 0; nt < 8; nt++) cb[nt] = cvec[nt * 16 + lm];
#pragma unroll
    for (int mt = 0; mt < 2; mt++)
#pragma unroll
        for (int r = 0; r < 4; r++) {
            int row = m0 + wv * 32 + mt * 16 + quad * 4 + r;
#pragma unroll
            for (int nt = 0; nt < 8; nt++) {
                int col = nt * 16 + lm;
                out[(size_t)row * OUT_F + col] = acc[mt][nt][r] + cb[nt];
            }
        }
}

// ---------------------------------------------------------------------------
extern "C" void kernel_launch(void* const* d_in, const int* in_sizes, int n_in,
                              void* d_out, int out_size, void* d_ws, size_t ws_size,
                              hipStream_t stream) {
    const float* x    = (const float*)d_in[0];
    const int*   ei   = (const int*)d_in[1];
    const float* Wb   = (const float*)d_in[2];
    const float* bb   = (const float*)d_in[3];
    const float* W1   = (const float*)d_in[4];
    const float* b1   = (const float*)d_in[5];
    const float* W2   = (const float*)d_in[6];
    const float* b2   = (const float*)d_in[7];
    const float* bg   = (const float*)d_in[8];
    const float* temp = (const float*)d_in[9];
    const float* Wo   = (const float*)d_in[10];
    const float* bo   = (const float*)d_in[11];
    float* out = (float*)d_out;

    char* w = (char*)d_ws;
    size_t used = 0;
    auto alloc = [&](size_t bytes) {
        char* p = w + used;
        used += (bytes + 255) & ~(size_t)255;
        return p;
    };
    int*    deg    = (int*)alloc(N_NODES * 4);
    int*    flag   = (int*)alloc(4);
    int*    row32  = (int*)alloc(N_EDGES * 4);
    int*    col32  = (int*)alloc(N_EDGES * 4);
    int*    offs   = (int*)alloc((N_NODES + 2) * 4);
    int*    cursor = (int*)alloc(N_NODES * 4);
    int*    srcs   = (int*)alloc(N_EDGES * 4);
    float*  invd   = (float*)alloc(N_NODES * 4);
    float*  mbuf   = (float*)alloc((size_t)NB * N_NODES * 4);
    float*  gates  = (float*)alloc(64 * 4);
    float*  u      = (float*)alloc(NB * OUT_F * 4);
    float*  cvec   = (float*)alloc(OUT_F * 4);
    ushort* WcT    = (ushort*)alloc((size_t)NB * IN_F * OUT_F * 2);
    ushort* WzT    = (ushort*)alloc((size_t)NB * OUT_F * OUT_F * 2);
    ushort* xb     = (ushort*)alloc((size_t)N_NODES * IN_F * 2);
    ushort* X1b    = (ushort*)alloc((size_t)N_NODES * IN_F * 2);
    ushort* X2b    = (ushort*)alloc((size_t)N_NODES * IN_F * 2);
    ushort* X3b    = (ushort*)alloc((size_t)N_NODES * IN_F * 2);
    ushort* R      = (ushort*)alloc((size_t)N_NODES * NB * OUT_F * 2);
    if (used > ws_size) return;

    float* m0v = mbuf;
    float* m1v = mbuf + N_NODES;
    float* m2v = mbuf + 2 * N_NODES;
    float* m3v = mbuf + 3 * N_NODES;

    hipMemsetAsync(deg, 0, N_NODES * 4, stream);
    hipMemsetAsync(flag, 0, 4, stream);

    detect_kernel<<<1, 64, 0, stream>>>(ei, flag);
    repack_count_kernel<<<N_EDGES / 256, 256, 0, stream>>>(ei, flag, row32, col32, deg);
    scan_kernel<<<1, 1024, 0, stream>>>(deg, offs, cursor, invd, m0v);
    fill_csr_kernel<<<N_EDGES / 256, 256, 0, stream>>>(row32, col32, cursor, srcs);

    prep_misc_kernel<<<1, 128, 0, stream>>>(bg, temp, bb, W1, b2, Wo, bo, gates, u, cvec);
    prep_wc_kernel<<<NB * IN_F, 128, 0, stream>>>(Wb, W1, WcT);
    prep_wz_kernel<<<NB * OUT_F, 128, 0, stream>>>(W2, Wo, gates, WzT);
    convert_bf16_kernel<<<(N_NODES * IN_F / 4) / 256, 256, 0, stream>>>(x, xb);

    prop_m_kernel<<<N_NODES / 256, 256, 0, stream>>>(m0v, m1v, offs, srcs, invd);
    prop_m_kernel<<<N_NODES / 256, 256, 0, stream>>>(m1v, m2v, offs, srcs, invd);
    prop_m_kernel<<<N_NODES / 256, 256, 0, stream>>>(m2v, m3v, offs, srcs, invd);

    prop_x_bf16_kernel<<<N_NODES / 4, 256, 0, stream>>>(xb, X1b, offs, srcs, invd);
    prop_x_bf16_kernel<<<N_NODES / 4, 256, 0, stream>>>(X1b, X2b, offs, srcs, invd);
    prop_x_bf16_kernel<<<N_NODES / 4, 256, 0, stream>>>(X2b, X3b, offs, srcs, invd);

    {
        dim3 grid(N_NODES / 128, NB);
        gemm1_mfma_kernel<<<grid, 256, 0, stream>>>(xb, X1b, X2b, X3b, WcT, u, b1, mbuf, R);
    }
    gemm2_mfma_kernel<<<N_NODES / 128, 256, 0, stream>>>(R, WzT, cvec, out);
}

// Round 4
// 345.166 us; speedup vs baseline: 1.9899x; 1.2111x over previous
//
#include <hip/hip_runtime.h>
#include <math.h>

#define N_NODES 32768
#define N_EDGES 524288
#define IN_F    256
#define OUT_F   128
#define NB      4

typedef __attribute__((ext_vector_type(8))) short bf16x8;
typedef __attribute__((ext_vector_type(4))) float f32x4;

__device__ __forceinline__ ushort f2b(float f) {  // f32 -> bf16 RNE
    uint u = __float_as_uint(f);
    return (ushort)((u + 0x7fffu + ((u >> 16) & 1u)) >> 16);
}
__device__ __forceinline__ float b2f_lo(uint v) { return __uint_as_float(v << 16); }
__device__ __forceinline__ float b2f_hi(uint v) { return __uint_as_float(v & 0xffff0000u); }

// ---------------------------------------------------------------------------
// Edge dtype detection + repack + degree count
// ---------------------------------------------------------------------------
__global__ void detect_kernel(const int* __restrict__ ei, int* __restrict__ flag) {
    int t = threadIdx.x;  // 64 threads
    if (ei[2 * t + 1] != 0) atomicOr(flag, 1);  // flag=1 -> int32 layout
}

__global__ void repack_count_kernel(const int* __restrict__ ei, const int* __restrict__ flag,
                                    int* __restrict__ row32, int* __restrict__ col32,
                                    int* __restrict__ deg) {
    int e = blockIdx.x * 256 + threadIdx.x;
    if (e >= N_EDGES) return;
    int r, c;
    if (*flag == 0) {
        r = ei[2 * e];
        c = ei[2 * (N_EDGES + e)];
    } else {
        r = ei[e];
        c = ei[N_EDGES + e];
    }
    row32[e] = r;
    col32[e] = c;
    atomicAdd(&deg[c], 1);
}

// ---------------------------------------------------------------------------
// 3-phase parallel exclusive scan of deg[32768]
// ---------------------------------------------------------------------------
__global__ __launch_bounds__(256) void scan1_kernel(const int* __restrict__ deg,
                                                    int* __restrict__ bsum) {
    int t = threadIdx.x;
    int v = deg[blockIdx.x * 256 + t];
    __shared__ int red[4];
    int lane = t & 63, wv = t >> 6;
#pragma unroll
    for (int off = 32; off > 0; off >>= 1) v += __shfl_down(v, off);
    if (lane == 0) red[wv] = v;
    __syncthreads();
    if (t == 0) bsum[blockIdx.x] = red[0] + red[1] + red[2] + red[3];
}

__global__ __launch_bounds__(128) void scan2_kernel(const int* __restrict__ bsum,
                                                    int* __restrict__ bbase,
                                                    int* __restrict__ offs) {
    __shared__ int s[128];
    int t = threadIdx.x;
    int v = bsum[t];
    s[t] = v;
    __syncthreads();
    for (int off = 1; off < 128; off <<= 1) {
        int add = (t >= off) ? s[t - off] : 0;
        __syncthreads();
        s[t] += add;
        __syncthreads();
    }
    bbase[t] = s[t] - v;                 // exclusive block base
    if (t == 127) offs[N_NODES] = s[127];
}

__global__ __launch_bounds__(256) void scan3_kernel(
    const int* __restrict__ deg, const int* __restrict__ bbase,
    int* __restrict__ offs, int* __restrict__ cursor,
    float* __restrict__ invd, float* __restrict__ m0, float* __restrict__ m1) {
    __shared__ int s[256];
    int t = threadIdx.x;
    int idx = blockIdx.x * 256 + t;
    int d = deg[idx];
    s[t] = d;
    __syncthreads();
    for (int off = 1; off < 256; off <<= 1) {
        int add = (t >= off) ? s[t - off] : 0;
        __syncthreads();
        s[t] += add;
        __syncthreads();
    }
    int excl = bbase[blockIdx.x] + s[t] - d;
    offs[idx] = excl;
    cursor[idx] = excl;
    invd[idx] = 1.0f / (float)((d > 1) ? d : 1);
    m0[idx] = 1.0f;
    m1[idx] = (d > 0) ? 1.0f : 0.0f;  // A . ones  (deg/max(deg,1))
}

__global__ void fill_csr_kernel(const int* __restrict__ row32, const int* __restrict__ col32,
                                int* __restrict__ cursor, int* __restrict__ srcs) {
    int e = blockIdx.x * 256 + threadIdx.x;
    if (e >= N_EDGES) return;
    int c = col32[e];
    int slot = atomicAdd(&cursor[c], 1);
    srcs[slot] = row32[e];
}

// ---------------------------------------------------------------------------
// Small weight prep (parallel): gates, u_i = bb_i@W1_i, cvec = bo + sum g_i b2_i@Wo_i
// grid = 8 blocks x 512 threads. cvec must be pre-zeroed (atomic accumulate).
// ---------------------------------------------------------------------------
__global__ __launch_bounds__(512) void prep_small_kernel(
    const float* __restrict__ bg, const float* __restrict__ temp,
    const float* __restrict__ bb, const float* __restrict__ W1,
    const float* __restrict__ b2, const float* __restrict__ Wo,
    const float* __restrict__ bo,
    float* __restrict__ gates, float* __restrict__ u, float* __restrict__ cvec) {
    __shared__ float red[4][128];
    int tid = threadIdx.x;
    int jc = tid >> 7, f = tid & 127;
    float T = temp[0];
    float mx = fmaxf(fmaxf(bg[0], bg[1]), fmaxf(bg[2], bg[3]));
    float e0 = expf((bg[0] - mx) / T), e1 = expf((bg[1] - mx) / T);
    float e2 = expf((bg[2] - mx) / T), e3 = expf((bg[3] - mx) / T);
    float ssum = e0 + e1 + e2 + e3;
    float g[NB] = {e0 / ssum, e1 / ssum, e2 / ssum, e3 / ssum};

    int b = blockIdx.x;
    if (b < NB) {
        int i = b;
        float partial = 0.f;
#pragma unroll 8
        for (int j = jc * 32; j < jc * 32 + 32; j++)
            partial += bb[i * OUT_F + j] * W1[(i * OUT_F + j) * OUT_F + f];
        red[jc][f] = partial;
        __syncthreads();
        if (jc == 0) {
            u[i * OUT_F + f] = red[0][f] + red[1][f] + red[2][f] + red[3][f];
            if (i == 0 && f < NB) gates[f] = g[f];
        }
    } else {
        int i = b - NB;
        float partial = 0.f;
#pragma unroll 8
        for (int j = jc * 32; j < jc * 32 + 32; j++)
            partial += b2[i * OUT_F + j] * Wo[(i * OUT_F + j) * OUT_F + f];
        red[jc][f] = partial;
        __syncthreads();
        if (jc == 0) {
            float tot = (red[0][f] + red[1][f] + red[2][f] + red[3][f]) * g[i];
            if (i == 0) tot += bo[f];
            atomicAdd(&cvec[f], tot);
        }
    }
}

// ---------------------------------------------------------------------------
// Big weight prep (merged): blocks [0,1024) WcT, [1024,1536) WzT
// WcT[i][f][k] = sum_j Wb[i][k][j]*W1[i][j][f];  WzT[f][128i+j] = g_i*sum_l W2[i][j][l]*Wo[128i+l][f]
// ---------------------------------------------------------------------------
__global__ __launch_bounds__(128) void prep_w_kernel(
    const float* __restrict__ Wb, const float* __restrict__ W1,
    const float* __restrict__ W2, const float* __restrict__ Wo,
    const float* __restrict__ gates,
    ushort* __restrict__ WcT, ushort* __restrict__ WzT) {
    int b = blockIdx.x;
    __shared__ float wrow[OUT_F];
    int f = threadIdx.x;
    if (b < NB * IN_F) {
        int i = b >> 8, k = b & 255;
        wrow[f] = Wb[(i * IN_F + k) * OUT_F + f];
        __syncthreads();
        const float* W1i = W1 + i * OUT_F * OUT_F;
        float acc = 0.f;
#pragma unroll 4
        for (int j = 0; j < OUT_F; j++) acc += wrow[j] * W1i[j * OUT_F + f];
        WcT[(size_t)(i * OUT_F + f) * IN_F + k] = f2b(acc);
    } else {
        int bb2 = b - NB * IN_F;
        int i = bb2 >> 7, j = bb2 & 127;
        wrow[f] = W2[(i * OUT_F + j) * OUT_F + f];
        __syncthreads();
        float acc = 0.f;
#pragma unroll 4
        for (int l = 0; l < OUT_F; l++) acc += wrow[l] * Wo[(i * OUT_F + l) * OUT_F + f];
        WzT[(size_t)f * (NB * OUT_F) + i * OUT_F + j] = f2b(gates[i] * acc);
    }
}

// x (f32) -> xb (bf16)
__global__ __launch_bounds__(256) void convert_bf16_kernel(
    const float* __restrict__ x, ushort* __restrict__ xb) {
    int idx = blockIdx.x * 256 + threadIdx.x;  // 4 floats each
    float4 v = ((const float4*)x)[idx];
    ushort4 o;
    o.x = f2b(v.x); o.y = f2b(v.y); o.z = f2b(v.z); o.w = f2b(v.w);
    ((ushort4*)xb)[idx] = o;
}

// ---------------------------------------------------------------------------
// Fused propagation: blocks [0, 8192) do X (one wave per node, 2 half-waves x
// unroll 2 = 4 gathers in flight); blocks [8192, 8320) do the scalar m-vector.
// ---------------------------------------------------------------------------
__global__ __launch_bounds__(256) void prop_fused_kernel(
    const ushort* __restrict__ in, ushort* __restrict__ out,
    const float* __restrict__ m_in, float* __restrict__ m_out, int do_m,
    const int* __restrict__ offs, const int* __restrict__ srcs,
    const float* __restrict__ invd) {
    int blk = blockIdx.x;
    if (blk >= N_NODES / 4) {  // m part
        int n = (blk - N_NODES / 4) * 256 + threadIdx.x;
        int s = offs[n], e = offs[n + 1];
        float sum = 0.f;
        for (int p = s; p < e; ++p) sum += m_in[srcs[p]];
        m_out[n] = sum * invd[n];
        return;
    }
    int node = blk * 4 + (threadIdx.x >> 6);
    int lane = threadIdx.x & 63;
    int half = lane >> 5;
    int fl   = lane & 31;
    int s = offs[node], e = offs[node + 1];

    float a0[8] = {0.f, 0.f, 0.f, 0.f, 0.f, 0.f, 0.f, 0.f};
    float a1[8] = {0.f, 0.f, 0.f, 0.f, 0.f, 0.f, 0.f, 0.f};

    int p = s;
    for (; p + 4 <= e; p += 4) {
        int2 ss = *(const int2*)(srcs + p + 2 * half);
        uint4 v0 = *(const uint4*)(in + (size_t)ss.x * IN_F + fl * 8);
        uint4 v1 = *(const uint4*)(in + (size_t)ss.y * IN_F + fl * 8);
        a0[0] += b2f_lo(v0.x); a0[1] += b2f_hi(v0.x);
        a0[2] += b2f_lo(v0.y); a0[3] += b2f_hi(v0.y);
        a0[4] += b2f_lo(v0.z); a0[5] += b2f_hi(v0.z);
        a0[6] += b2f_lo(v0.w); a0[7] += b2f_hi(v0.w);
        a1[0] += b2f_lo(v1.x); a1[1] += b2f_hi(v1.x);
        a1[2] += b2f_lo(v1.y); a1[3] += b2f_hi(v1.y);
        a1[4] += b2f_lo(v1.z); a1[5] += b2f_hi(v1.z);
        a1[6] += b2f_lo(v1.w); a1[7] += b2f_hi(v1.w);
    }
    for (; p + half < e; p += 2) {
        int src = srcs[p + half];
        uint4 v0 = *(const uint4*)(in + (size_t)src * IN_F + fl * 8);
        a0[0] += b2f_lo(v0.x); a0[1] += b2f_hi(v0.x);
        a0[2] += b2f_lo(v0.y); a0[3] += b2f_hi(v0.y);
        a0[4] += b2f_lo(v0.z); a0[5] += b2f_hi(v0.z);
        a0[6] += b2f_lo(v0.w); a0[7] += b2f_hi(v0.w);
    }
#pragma unroll
    for (int k = 0; k < 8; k++) a0[k] += a1[k];
#pragma unroll
    for (int k = 0; k < 8; k++) a0[k] += __shfl_down(a0[k], 32);

    if (half == 0) {
        float w = invd[node];
        uint4 o;
        o.x = (uint)f2b(a0[0] * w) | ((uint)f2b(a0[1] * w) << 16);
        o.y = (uint)f2b(a0[2] * w) | ((uint)f2b(a0[3] * w) << 16);
        o.z = (uint)f2b(a0[4] * w) | ((uint)f2b(a0[5] * w) << 16);
        o.w = (uint)f2b(a0[6] * w) | ((uint)f2b(a0[7] * w) << 16);
        *(uint4*)(out + (size_t)node * IN_F + fl * 8) = o;
    }
}

// ---------------------------------------------------------------------------
// GEMM1 (MFMA): R[:,128b:128b+128] = relu(X_b @ Wc_b + m_b*u_b + b1_b), bf16 out
// ---------------------------------------------------------------------------
__global__ __launch_bounds__(256) void gemm1_mfma_kernel(
    const ushort* __restrict__ A0, const ushort* __restrict__ A1,
    const ushort* __restrict__ A2, const ushort* __restrict__ A3,
    const ushort* __restrict__ WcT, const float* __restrict__ u,
    const float* __restrict__ b1, const float* __restrict__ m,
    ushort* __restrict__ R) {
    int branch = blockIdx.y;
    const ushort* A = (branch == 0) ? A0 : (branch == 1) ? A1 : (branch == 2) ? A2 : A3;
    const ushort* WT = WcT + (size_t)branch * OUT_F * IN_F;
    const float* mv = m + (size_t)branch * N_NODES;
    int m0 = blockIdx.x * 128;

    __shared__ ushort As[128][72];
    __shared__ ushort Bs[128][72];

    int tid = threadIdx.x;
    int wv = tid >> 6, lane = tid & 63, quad = lane >> 4, lm = lane & 15;

    f32x4 acc[2][8];
    f32x4 zero = {0.f, 0.f, 0.f, 0.f};
#pragma unroll
    for (int i = 0; i < 2; i++)
#pragma unroll
        for (int j = 0; j < 8; j++) acc[i][j] = zero;

    for (int k0 = 0; k0 < IN_F; k0 += 64) {
        __syncthreads();
#pragma unroll
        for (int it = 0; it < 4; it++) {
            int c = tid + 256 * it;
            int r = c >> 3, c8 = c & 7;
            *(uint4*)&As[r][c8 * 8] = *(const uint4*)(A + (size_t)(m0 + r) * IN_F + k0 + c8 * 8);
            *(uint4*)&Bs[r][c8 * 8] = *(const uint4*)(WT + (size_t)r * IN_F + k0 + c8 * 8);
        }
        __syncthreads();
#pragma unroll
        for (int ks = 0; ks < 2; ks++) {
            bf16x8 af0 = *(const bf16x8*)&As[wv * 32 + lm][ks * 32 + quad * 8];
            bf16x8 af1 = *(const bf16x8*)&As[wv * 32 + 16 + lm][ks * 32 + quad * 8];
#pragma unroll
            for (int nt = 0; nt < 8; nt++) {
                bf16x8 bf = *(const bf16x8*)&Bs[nt * 16 + lm][ks * 32 + quad * 8];
                acc[0][nt] = __builtin_amdgcn_mfma_f32_16x16x32_bf16(af0, bf, acc[0][nt], 0, 0, 0);
                acc[1][nt] = __builtin_amdgcn_mfma_f32_16x16x32_bf16(af1, bf, acc[1][nt], 0, 0, 0);
            }
        }
    }

    float uv[8], bv[8];
#pragma unroll
    for (int nt = 0; nt < 8; nt++) {
        int col = nt * 16 + lm;
        uv[nt] = u[branch * OUT_F + col];
        bv[nt] = b1[branch * OUT_F + col];
    }
#pragma unroll
    for (int mt = 0; mt < 2; mt++)
#pragma unroll
        for (int r = 0; r < 4; r++) {
            int row = m0 + wv * 32 + mt * 16 + quad * 4 + r;
            float mval = mv[row];
#pragma unroll
            for (int nt = 0; nt < 8; nt++) {
                int col = nt * 16 + lm;
                float h = acc[mt][nt][r] + mval * uv[nt] + bv[nt];
                R[(size_t)row * (NB * OUT_F) + branch * OUT_F + col] = f2b(fmaxf(h, 0.f));
            }
        }
}

// ---------------------------------------------------------------------------
// GEMM2 (MFMA): out = R[32768,512](bf16) @ Wz(bf16) + c  -> f32
// ---------------------------------------------------------------------------
__global__ __launch_bounds__(256) void gemm2_mfma_kernel(
    const ushort* __restrict__ R, const ushort* __restrict__ WzT,
    const float* __restrict__ cvec, float* __restrict__ out) {
    int m0 = blockIdx.x * 128;
    const int K = NB * OUT_F;  // 512

    __shared__ ushort As[128][72];
    __shared__ ushort Bs[128][72];

    int tid = threadIdx.x;
    int wv = tid >> 6, lane = tid & 63, quad = lane >> 4, lm = lane & 15;

    f32x4 acc[2][8];
    f32x4 zero = {0.f, 0.f, 0.f, 0.f};
#pragma unroll
    for (int i = 0; i < 2; i++)
#pragma unroll
        for (int j = 0; j < 8; j++) acc[i][j] = zero;

    for (int k0 = 0; k0 < K; k0 += 64) {
        __syncthreads();
#pragma unroll
        for (int it = 0; it < 4; it++) {
            int c = tid + 256 * it;
            int r = c >> 3, c8 = c & 7;
            *(uint4*)&As[r][c8 * 8] = *(const uint4*)(R + (size_t)(m0 + r) * K + k0 + c8 * 8);
            *(uint4*)&Bs[r][c8 * 8] = *(const uint4*)(WzT + (size_t)r * K + k0 + c8 * 8);
        }
        __syncthreads();
#pragma unroll
        for (int ks = 0; ks < 2; ks++) {
            bf16x8 af0 = *(const bf16x8*)&As[wv * 32 + lm][ks * 32 + quad * 8];
            bf16x8 af1 = *(const bf16x8*)&As[wv * 32 + 16 + lm][ks * 32 + quad * 8];
#pragma unroll
            for (int nt = 0; nt < 8; nt++) {
                bf16x8 bf = *(const bf16x8*)&Bs[nt * 16 + lm][ks * 32 + quad * 8];
                acc[0][nt] = __builtin_amdgcn_mfma_f32_16x16x32_bf16(af0, bf, acc[0][nt], 0, 0, 0);
                acc[1][nt] = __builtin_amdgcn_mfma_f32_16x16x32_bf16(af1, bf, acc[1][nt], 0, 0, 0);
            }
        }
    }

    float cb[8];
#pragma unroll
    for (int nt = 0; nt < 8; nt++) cb[nt] = cvec[nt * 16 + lm];
#pragma unroll
    for (int mt = 0; mt < 2; mt++)
#pragma unroll
        for (int r = 0; r < 4; r++) {
            int row = m0 + wv * 32 + mt * 16 + quad * 4 + r;
#pragma unroll
            for (int nt = 0; nt < 8; nt++) {
                int col = nt * 16 + lm;
                out[(size_t)row * OUT_F + col] = acc[mt][nt][r] + cb[nt];
            }
        }
}

// ---------------------------------------------------------------------------
extern "C" void kernel_launch(void* const* d_in, const int* in_sizes, int n_in,
                              void* d_out, int out_size, void* d_ws, size_t ws_size,
                              hipStream_t stream) {
    const float* x    = (const float*)d_in[0];
    const int*   ei   = (const int*)d_in[1];
    const float* Wb   = (const float*)d_in[2];
    const float* bb   = (const float*)d_in[3];
    const float* W1   = (const float*)d_in[4];
    const float* b1   = (const float*)d_in[5];
    const float* W2   = (const float*)d_in[6];
    const float* b2   = (const float*)d_in[7];
    const float* bg   = (const float*)d_in[8];
    const float* temp = (const float*)d_in[9];
    const float* Wo   = (const float*)d_in[10];
    const float* bo   = (const float*)d_in[11];
    float* out = (float*)d_out;

    char* w = (char*)d_ws;
    size_t used = 0;
    auto alloc = [&](size_t bytes) {
        char* p = w + used;
        used += (bytes + 255) & ~(size_t)255;
        return p;
    };
    // deg, cvec, flag contiguous -> single memset zeroes all three
    int*    deg    = (int*)alloc(N_NODES * 4);          // 131072 B
    float*  cvec   = (float*)alloc(OUT_F * 4);          // 512 B
    int*    flag   = (int*)alloc(4);                    // 256 B slot
    int*    row32  = (int*)alloc(N_EDGES * 4);
    int*    col32  = (int*)alloc(N_EDGES * 4);
    int*    offs   = (int*)alloc((N_NODES + 2) * 4);
    int*    cursor = (int*)alloc(N_NODES * 4);
    int*    srcs   = (int*)alloc(N_EDGES * 4);
    int*    bsum   = (int*)alloc(128 * 4);
    int*    bbase  = (int*)alloc(128 * 4);
    float*  invd   = (float*)alloc(N_NODES * 4);
    float*  mbuf   = (float*)alloc((size_t)NB * N_NODES * 4);
    float*  gates  = (float*)alloc(64 * 4);
    float*  u      = (float*)alloc(NB * OUT_F * 4);
    ushort* WcT    = (ushort*)alloc((size_t)NB * IN_F * OUT_F * 2);
    ushort* WzT    = (ushort*)alloc((size_t)NB * OUT_F * OUT_F * 2);
    ushort* xb     = (ushort*)alloc((size_t)N_NODES * IN_F * 2);
    ushort* X1b    = (ushort*)alloc((size_t)N_NODES * IN_F * 2);
    ushort* X2b    = (ushort*)alloc((size_t)N_NODES * IN_F * 2);
    ushort* X3b    = (ushort*)alloc((size_t)N_NODES * IN_F * 2);
    ushort* R      = (ushort*)alloc((size_t)N_NODES * NB * OUT_F * 2);
    if (used > ws_size) return;

    float* m0v = mbuf;
    float* m1v = mbuf + N_NODES;
    float* m2v = mbuf + 2 * N_NODES;
    float* m3v = mbuf + 3 * N_NODES;

    hipMemsetAsync(deg, 0, N_NODES * 4 + 512 + 256, stream);  // deg + cvec + flag

    detect_kernel<<<1, 64, 0, stream>>>(ei, flag);
    repack_count_kernel<<<N_EDGES / 256, 256, 0, stream>>>(ei, flag, row32, col32, deg);
    scan1_kernel<<<N_NODES / 256, 256, 0, stream>>>(deg, bsum);
    scan2_kernel<<<1, 128, 0, stream>>>(bsum, bbase, offs);
    scan3_kernel<<<N_NODES / 256, 256, 0, stream>>>(deg, bbase, offs, cursor, invd, m0v, m1v);
    fill_csr_kernel<<<N_EDGES / 256, 256, 0, stream>>>(row32, col32, cursor, srcs);

    prep_small_kernel<<<2 * NB, 512, 0, stream>>>(bg, temp, bb, W1, b2, Wo, bo, gates, u, cvec);
    prep_w_kernel<<<NB * IN_F + NB * OUT_F, 128, 0, stream>>>(Wb, W1, W2, Wo, gates, WcT, WzT);
    convert_bf16_kernel<<<(N_NODES * IN_F / 4) / 256, 256, 0, stream>>>(x, xb);

    // fused X + m propagation: X1=A.x (with m2=A.m1), X2=A.X1 (with m3=A.m2), X3=A.X2
    prop_fused_kernel<<<N_NODES / 4 + N_NODES / 256, 256, 0, stream>>>(
        xb, X1b, m1v, m2v, 1, offs, srcs, invd);
    prop_fused_kernel<<<N_NODES / 4 + N_NODES / 256, 256, 0, stream>>>(
        X1b, X2b, m2v, m3v, 1, offs, srcs, invd);
    prop_fused_kernel<<<N_NODES / 4, 256, 0, stream>>>(
        X2b, X3b, (const float*)nullptr, (float*)nullptr, 0, offs, srcs, invd);

    {
        dim3 grid(N_NODES / 128, NB);
        gemm1_mfma_kernel<<<grid, 256, 0, stream>>>(xb, X1b, X2b, X3b, WcT, u, b1, mbuf, R);
    }
    gemm2_mfma_kernel<<<N_NODES / 128, 256, 0, stream>>>(R, WzT, cvec, out);
}

// Round 5
// 341.748 us; speedup vs baseline: 2.0098x; 1.0100x over previous
//
#include <hip/hip_runtime.h>
#include <math.h>

#define N_NODES 32768
#define N_EDGES 524288
#define IN_F    256
#define OUT_F   128
#define NB      4

typedef __attribute__((ext_vector_type(8))) short bf16x8;
typedef __attribute__((ext_vector_type(4))) float f32x4;

__device__ __forceinline__ ushort f2b(float f) {  // f32 -> bf16 RNE
    uint u = __float_as_uint(f);
    return (ushort)((u + 0x7fffu + ((u >> 16) & 1u)) >> 16);
}
__device__ __forceinline__ float b2f_lo(uint v) { return __uint_as_float(v << 16); }
__device__ __forceinline__ float b2f_hi(uint v) { return __uint_as_float(v & 0xffff0000u); }

// ---------------------------------------------------------------------------
// Edge dtype detection + degree count (no repack buffers; ei read directly)
// ---------------------------------------------------------------------------
__global__ void detect_kernel(const int* __restrict__ ei, int* __restrict__ flag) {
    int t = threadIdx.x;  // 64 threads
    if (ei[2 * t + 1] != 0) atomicOr(flag, 1);  // flag=1 -> int32 layout
}

__global__ void count_kernel(const int* __restrict__ ei, const int* __restrict__ flag,
                             int* __restrict__ deg) {
    int e = blockIdx.x * 256 + threadIdx.x;
    if (e >= N_EDGES) return;
    int c = (*flag == 0) ? ei[2 * (N_EDGES + e)] : ei[N_EDGES + e];
    atomicAdd(&deg[c], 1);
}

// ---------------------------------------------------------------------------
// 3-phase parallel exclusive scan of deg[32768]
// ---------------------------------------------------------------------------
__global__ __launch_bounds__(256) void scan1_kernel(const int* __restrict__ deg,
                                                    int* __restrict__ bsum) {
    int t = threadIdx.x;
    int v = deg[blockIdx.x * 256 + t];
    __shared__ int red[4];
    int lane = t & 63, wv = t >> 6;
#pragma unroll
    for (int off = 32; off > 0; off >>= 1) v += __shfl_down(v, off);
    if (lane == 0) red[wv] = v;
    __syncthreads();
    if (t == 0) bsum[blockIdx.x] = red[0] + red[1] + red[2] + red[3];
}

__global__ __launch_bounds__(128) void scan2_kernel(const int* __restrict__ bsum,
                                                    int* __restrict__ bbase,
                                                    int* __restrict__ offs) {
    __shared__ int s[128];
    int t = threadIdx.x;
    int v = bsum[t];
    s[t] = v;
    __syncthreads();
    for (int off = 1; off < 128; off <<= 1) {
        int add = (t >= off) ? s[t - off] : 0;
        __syncthreads();
        s[t] += add;
        __syncthreads();
    }
    bbase[t] = s[t] - v;                 // exclusive block base
    if (t == 127) offs[N_NODES] = s[127];
}

__global__ __launch_bounds__(256) void scan3_kernel(
    const int* __restrict__ deg, const int* __restrict__ bbase,
    int* __restrict__ offs, int* __restrict__ cursor,
    float* __restrict__ invd, float* __restrict__ m0, float* __restrict__ m1) {
    __shared__ int s[256];
    int t = threadIdx.x;
    int idx = blockIdx.x * 256 + t;
    int d = deg[idx];
    s[t] = d;
    __syncthreads();
    for (int off = 1; off < 256; off <<= 1) {
        int add = (t >= off) ? s[t - off] : 0;
        __syncthreads();
        s[t] += add;
        __syncthreads();
    }
    int excl = bbase[blockIdx.x] + s[t] - d;
    offs[idx] = excl;
    cursor[idx] = excl;
    invd[idx] = 1.0f / (float)((d > 1) ? d : 1);
    m0[idx] = 1.0f;
    m1[idx] = (d > 0) ? 1.0f : 0.0f;  // A . ones
}

__global__ void fill_csr_kernel(const int* __restrict__ ei, const int* __restrict__ flag,
                                int* __restrict__ cursor, int* __restrict__ srcs) {
    int e = blockIdx.x * 256 + threadIdx.x;
    if (e >= N_EDGES) return;
    int r, c;
    if (*flag == 0) {
        r = ei[2 * e];
        c = ei[2 * (N_EDGES + e)];
    } else {
        r = ei[e];
        c = ei[N_EDGES + e];
    }
    int slot = atomicAdd(&cursor[c], 1);
    srcs[slot] = r;
}

// ---------------------------------------------------------------------------
// Small weight prep (parallel): gates, u_i = bb_i@W1_i, cvec = bo + sum g_i b2_i@Wo_i
// grid = 8 blocks x 512 threads. cvec must be pre-zeroed (atomic accumulate).
// ---------------------------------------------------------------------------
__global__ __launch_bounds__(512) void prep_small_kernel(
    const float* __restrict__ bg, const float* __restrict__ temp,
    const float* __restrict__ bb, const float* __restrict__ W1,
    const float* __restrict__ b2, const float* __restrict__ Wo,
    const float* __restrict__ bo,
    float* __restrict__ gates, float* __restrict__ u, float* __restrict__ cvec) {
    __shared__ float red[4][128];
    int tid = threadIdx.x;
    int jc = tid >> 7, f = tid & 127;
    float T = temp[0];
    float mx = fmaxf(fmaxf(bg[0], bg[1]), fmaxf(bg[2], bg[3]));
    float e0 = expf((bg[0] - mx) / T), e1 = expf((bg[1] - mx) / T);
    float e2 = expf((bg[2] - mx) / T), e3 = expf((bg[3] - mx) / T);
    float ssum = e0 + e1 + e2 + e3;
    float g[NB] = {e0 / ssum, e1 / ssum, e2 / ssum, e3 / ssum};

    int b = blockIdx.x;
    if (b < NB) {
        int i = b;
        float partial = 0.f;
#pragma unroll 8
        for (int j = jc * 32; j < jc * 32 + 32; j++)
            partial += bb[i * OUT_F + j] * W1[(i * OUT_F + j) * OUT_F + f];
        red[jc][f] = partial;
        __syncthreads();
        if (jc == 0) {
            u[i * OUT_F + f] = red[0][f] + red[1][f] + red[2][f] + red[3][f];
            if (i == 0 && f < NB) gates[f] = g[f];
        }
    } else {
        int i = b - NB;
        float partial = 0.f;
#pragma unroll 8
        for (int j = jc * 32; j < jc * 32 + 32; j++)
            partial += b2[i * OUT_F + j] * Wo[(i * OUT_F + j) * OUT_F + f];
        red[jc][f] = partial;
        __syncthreads();
        if (jc == 0) {
            float tot = (red[0][f] + red[1][f] + red[2][f] + red[3][f]) * g[i];
            if (i == 0) tot += bo[f];
            atomicAdd(&cvec[f], tot);
        }
    }
}

// ---------------------------------------------------------------------------
// Big weight prep (merged): blocks [0,1024) WcT, [1024,1536) WzT
// ---------------------------------------------------------------------------
__global__ __launch_bounds__(128) void prep_w_kernel(
    const float* __restrict__ Wb, const float* __restrict__ W1,
    const float* __restrict__ W2, const float* __restrict__ Wo,
    const float* __restrict__ gates,
    ushort* __restrict__ WcT, ushort* __restrict__ WzT) {
    int b = blockIdx.x;
    __shared__ float wrow[OUT_F];
    int f = threadIdx.x;
    if (b < NB * IN_F) {
        int i = b >> 8, k = b & 255;
        wrow[f] = Wb[(i * IN_F + k) * OUT_F + f];
        __syncthreads();
        const float* W1i = W1 + i * OUT_F * OUT_F;
        float acc = 0.f;
#pragma unroll 4
        for (int j = 0; j < OUT_F; j++) acc += wrow[j] * W1i[j * OUT_F + f];
        WcT[(size_t)(i * OUT_F + f) * IN_F + k] = f2b(acc);
    } else {
        int bb2 = b - NB * IN_F;
        int i = bb2 >> 7, j = bb2 & 127;
        wrow[f] = W2[(i * OUT_F + j) * OUT_F + f];
        __syncthreads();
        float acc = 0.f;
#pragma unroll 4
        for (int l = 0; l < OUT_F; l++) acc += wrow[l] * Wo[(i * OUT_F + l) * OUT_F + f];
        WzT[(size_t)f * (NB * OUT_F) + i * OUT_F + j] = f2b(gates[i] * acc);
    }
}

// x (f32) -> xb (bf16)
__global__ __launch_bounds__(256) void convert_bf16_kernel(
    const float* __restrict__ x, ushort* __restrict__ xb) {
    int idx = blockIdx.x * 256 + threadIdx.x;  // 4 floats each
    float4 v = ((const float4*)x)[idx];
    ushort4 o;
    o.x = f2b(v.x); o.y = f2b(v.y); o.z = f2b(v.z); o.w = f2b(v.w);
    ((ushort4*)xb)[idx] = o;
}

// ---------------------------------------------------------------------------
// Fused propagation: blocks [0, 8192) do X (one wave per node, 2 half-waves,
// 4 edges per half per iteration => 8 gathers in flight); blocks [8192, 8320)
// do the scalar m-vector.
// ---------------------------------------------------------------------------
__global__ __launch_bounds__(256) void prop_fused_kernel(
    const ushort* __restrict__ in, ushort* __restrict__ out,
    const float* __restrict__ m_in, float* __restrict__ m_out, int do_m,
    const int* __restrict__ offs, const int* __restrict__ srcs,
    const float* __restrict__ invd) {
    int blk = blockIdx.x;
    if (blk >= N_NODES / 4) {  // m part
        int n = (blk - N_NODES / 4) * 256 + threadIdx.x;
        int s = offs[n], e = offs[n + 1];
        float sum = 0.f;
        for (int p = s; p < e; ++p) sum += m_in[srcs[p]];
        m_out[n] = sum * invd[n];
        return;
    }
    int node = blk * 4 + (threadIdx.x >> 6);
    int lane = threadIdx.x & 63;
    int half = lane >> 5;
    int fl   = lane & 31;
    int s = offs[node], e = offs[node + 1];

    float a0[8] = {0.f, 0.f, 0.f, 0.f, 0.f, 0.f, 0.f, 0.f};
    float a1[8] = {0.f, 0.f, 0.f, 0.f, 0.f, 0.f, 0.f, 0.f};

    int p = s;
    // main: 8 edges/iter, 4 per half-wave (4 x uint4 loads in flight per half)
    for (; p + 8 <= e; p += 8) {
        int base = p + 4 * half;
        int2 s01 = *(const int2*)(srcs + base);
        int2 s23 = *(const int2*)(srcs + base + 2);
        uint4 v0 = *(const uint4*)(in + (size_t)s01.x * IN_F + fl * 8);
        uint4 v1 = *(const uint4*)(in + (size_t)s01.y * IN_F + fl * 8);
        uint4 v2 = *(const uint4*)(in + (size_t)s23.x * IN_F + fl * 8);
        uint4 v3 = *(const uint4*)(in + (size_t)s23.y * IN_F + fl * 8);
        a0[0] += b2f_lo(v0.x); a0[1] += b2f_hi(v0.x);
        a0[2] += b2f_lo(v0.y); a0[3] += b2f_hi(v0.y);
        a0[4] += b2f_lo(v0.z); a0[5] += b2f_hi(v0.z);
        a0[6] += b2f_lo(v0.w); a0[7] += b2f_hi(v0.w);
        a1[0] += b2f_lo(v1.x); a1[1] += b2f_hi(v1.x);
        a1[2] += b2f_lo(v1.y); a1[3] += b2f_hi(v1.y);
        a1[4] += b2f_lo(v1.z); a1[5] += b2f_hi(v1.z);
        a1[6] += b2f_lo(v1.w); a1[7] += b2f_hi(v1.w);
        a0[0] += b2f_lo(v2.x); a0[1] += b2f_hi(v2.x);
        a0[2] += b2f_lo(v2.y); a0[3] += b2f_hi(v2.y);
        a0[4] += b2f_lo(v2.z); a0[5] += b2f_hi(v2.z);
        a0[6] += b2f_lo(v2.w); a0[7] += b2f_hi(v2.w);
        a1[0] += b2f_lo(v3.x); a1[1] += b2f_hi(v3.x);
        a1[2] += b2f_lo(v3.y); a1[3] += b2f_hi(v3.y);
        a1[4] += b2f_lo(v3.z); a1[5] += b2f_hi(v3.z);
        a1[6] += b2f_lo(v3.w); a1[7] += b2f_hi(v3.w);
    }
    // 4-edge chunk
    for (; p + 4 <= e; p += 4) {
        int2 ss = *(const int2*)(srcs + p + 2 * half);
        uint4 v0 = *(const uint4*)(in + (size_t)ss.x * IN_F + fl * 8);
        uint4 v1 = *(const uint4*)(in + (size_t)ss.y * IN_F + fl * 8);
        a0[0] += b2f_lo(v0.x); a0[1] += b2f_hi(v0.x);
        a0[2] += b2f_lo(v0.y); a0[3] += b2f_hi(v0.y);
        a0[4] += b2f_lo(v0.z); a0[5] += b2f_hi(v0.z);
        a0[6] += b2f_lo(v0.w); a0[7] += b2f_hi(v0.w);
        a1[0] += b2f_lo(v1.x); a1[1] += b2f_hi(v1.x);
        a1[2] += b2f_lo(v1.y); a1[3] += b2f_hi(v1.y);
        a1[4] += b2f_lo(v1.z); a1[5] += b2f_hi(v1.z);
        a1[6] += b2f_lo(v1.w); a1[7] += b2f_hi(v1.w);
    }
    // remainder (0..3 edges): half 0 -> edge p, half 1 -> edge p+1
    for (; p + half < e; p += 2) {
        int src = srcs[p + half];
        uint4 v0 = *(const uint4*)(in + (size_t)src * IN_F + fl * 8);
        a0[0] += b2f_lo(v0.x); a0[1] += b2f_hi(v0.x);
        a0[2] += b2f_lo(v0.y); a0[3] += b2f_hi(v0.y);
        a0[4] += b2f_lo(v0.z); a0[5] += b2f_hi(v0.z);
        a0[6] += b2f_lo(v0.w); a0[7] += b2f_hi(v0.w);
    }
#pragma unroll
    for (int k = 0; k < 8; k++) a0[k] += a1[k];
#pragma unroll
    for (int k = 0; k < 8; k++) a0[k] += __shfl_down(a0[k], 32);

    if (half == 0) {
        float w = invd[node];
        uint4 o;
        o.x = (uint)f2b(a0[0] * w) | ((uint)f2b(a0[1] * w) << 16);
        o.y = (uint)f2b(a0[2] * w) | ((uint)f2b(a0[3] * w) << 16);
        o.z = (uint)f2b(a0[4] * w) | ((uint)f2b(a0[5] * w) << 16);
        o.w = (uint)f2b(a0[6] * w) | ((uint)f2b(a0[7] * w) << 16);
        *(uint4*)(out + (size_t)node * IN_F + fl * 8) = o;
    }
}

// ---------------------------------------------------------------------------
// GEMM1 (MFMA): R[:,128b:128b+128] = relu(X_b @ Wc_b + m_b*u_b + b1_b), bf16 out
// ---------------------------------------------------------------------------
__global__ __launch_bounds__(256) void gemm1_mfma_kernel(
    const ushort* __restrict__ A0, const ushort* __restrict__ A1,
    const ushort* __restrict__ A2, const ushort* __restrict__ A3,
    const ushort* __restrict__ WcT, const float* __restrict__ u,
    const float* __restrict__ b1, const float* __restrict__ m,
    ushort* __restrict__ R) {
    int branch = blockIdx.y;
    const ushort* A = (branch == 0) ? A0 : (branch == 1) ? A1 : (branch == 2) ? A2 : A3;
    const ushort* WT = WcT + (size_t)branch * OUT_F * IN_F;
    const float* mv = m + (size_t)branch * N_NODES;
    int m0 = blockIdx.x * 128;

    __shared__ ushort As[128][72];
    __shared__ ushort Bs[128][72];

    int tid = threadIdx.x;
    int wv = tid >> 6, lane = tid & 63, quad = lane >> 4, lm = lane & 15;

    f32x4 acc[2][8];
    f32x4 zero = {0.f, 0.f, 0.f, 0.f};
#pragma unroll
    for (int i = 0; i < 2; i++)
#pragma unroll
        for (int j = 0; j < 8; j++) acc[i][j] = zero;

    for (int k0 = 0; k0 < IN_F; k0 += 64) {
        __syncthreads();
#pragma unroll
        for (int it = 0; it < 4; it++) {
            int c = tid + 256 * it;
            int r = c >> 3, c8 = c & 7;
            *(uint4*)&As[r][c8 * 8] = *(const uint4*)(A + (size_t)(m0 + r) * IN_F + k0 + c8 * 8);
            *(uint4*)&Bs[r][c8 * 8] = *(const uint4*)(WT + (size_t)r * IN_F + k0 + c8 * 8);
        }
        __syncthreads();
#pragma unroll
        for (int ks = 0; ks < 2; ks++) {
            bf16x8 af0 = *(const bf16x8*)&As[wv * 32 + lm][ks * 32 + quad * 8];
            bf16x8 af1 = *(const bf16x8*)&As[wv * 32 + 16 + lm][ks * 32 + quad * 8];
#pragma unroll
            for (int nt = 0; nt < 8; nt++) {
                bf16x8 bf = *(const bf16x8*)&Bs[nt * 16 + lm][ks * 32 + quad * 8];
                acc[0][nt] = __builtin_amdgcn_mfma_f32_16x16x32_bf16(af0, bf, acc[0][nt], 0, 0, 0);
                acc[1][nt] = __builtin_amdgcn_mfma_f32_16x16x32_bf16(af1, bf, acc[1][nt], 0, 0, 0);
            }
        }
    }

    float uv[8], bv[8];
#pragma unroll
    for (int nt = 0; nt < 8; nt++) {
        int col = nt * 16 + lm;
        uv[nt] = u[branch * OUT_F + col];
        bv[nt] = b1[branch * OUT_F + col];
    }
#pragma unroll
    for (int mt = 0; mt < 2; mt++)
#pragma unroll
        for (int r = 0; r < 4; r++) {
            int row = m0 + wv * 32 + mt * 16 + quad * 4 + r;
            float mval = mv[row];
#pragma unroll
            for (int nt = 0; nt < 8; nt++) {
                int col = nt * 16 + lm;
                float h = acc[mt][nt][r] + mval * uv[nt] + bv[nt];
                R[(size_t)row * (NB * OUT_F) + branch * OUT_F + col] = f2b(fmaxf(h, 0.f));
            }
        }
}

// ---------------------------------------------------------------------------
// GEMM2 (MFMA): out = R[32768,512](bf16) @ Wz(bf16) + c  -> f32
// ---------------------------------------------------------------------------
__global__ __launch_bounds__(256) void gemm2_mfma_kernel(
    const ushort* __restrict__ R, const ushort* __restrict__ WzT,
    const float* __restrict__ cvec, float* __restrict__ out) {
    int m0 = blockIdx.x * 128;
    const int K = NB * OUT_F;  // 512

    __shared__ ushort As[128][72];
    __shared__ ushort Bs[128][72];

    int tid = threadIdx.x;
    int wv = tid >> 6, lane = tid & 63, quad = lane >> 4, lm = lane & 15;

    f32x4 acc[2][8];
    f32x4 zero = {0.f, 0.f, 0.f, 0.f};
#pragma unroll
    for (int i = 0; i < 2; i++)
#pragma unroll
        for (int j = 0; j < 8; j++) acc[i][j] = zero;

    for (int k0 = 0; k0 < K; k0 += 64) {
        __syncthreads();
#pragma unroll
        for (int it = 0; it < 4; it++) {
            int c = tid + 256 * it;
            int r = c >> 3, c8 = c & 7;
            *(uint4*)&As[r][c8 * 8] = *(const uint4*)(R + (size_t)(m0 + r) * K + k0 + c8 * 8);
            *(uint4*)&Bs[r][c8 * 8] = *(const uint4*)(WzT + (size_t)r * K + k0 + c8 * 8);
        }
        __syncthreads();
#pragma unroll
        for (int ks = 0; ks < 2; ks++) {
            bf16x8 af0 = *(const bf16x8*)&As[wv * 32 + lm][ks * 32 + quad * 8];
            bf16x8 af1 = *(const bf16x8*)&As[wv * 32 + 16 + lm][ks * 32 + quad * 8];
#pragma unroll
            for (int nt = 0; nt < 8; nt++) {
                bf16x8 bf = *(const bf16x8*)&Bs[nt * 16 + lm][ks * 32 + quad * 8];
                acc[0][nt] = __builtin_amdgcn_mfma_f32_16x16x32_bf16(af0, bf, acc[0][nt], 0, 0, 0);
                acc[1][nt] = __builtin_amdgcn_mfma_f32_16x16x32_bf16(af1, bf, acc[1][nt], 0, 0, 0);
            }
        }
    }

    float cb[8];
#pragma unroll
    for (int nt = 0; nt < 8; nt++) cb[nt] = cvec[nt * 16 + lm];
#pragma unroll
    for (int mt = 0; mt < 2; mt++)
#pragma unroll
        for (int r = 0; r < 4; r++) {
            int row = m0 + wv * 32 + mt * 16 + quad * 4 + r;
#pragma unroll
            for (int nt = 0; nt < 8; nt++) {
                int col = nt * 16 + lm;
                out[(size_t)row * OUT_F + col] = acc[mt][nt][r] + cb[nt];
            }
        }
}

// ---------------------------------------------------------------------------
extern "C" void kernel_launch(void* const* d_in, const int* in_sizes, int n_in,
                              void* d_out, int out_size, void* d_ws, size_t ws_size,
                              hipStream_t stream) {
    const float* x    = (const float*)d_in[0];
    const int*   ei   = (const int*)d_in[1];
    const float* Wb   = (const float*)d_in[2];
    const float* bb   = (const float*)d_in[3];
    const float* W1   = (const float*)d_in[4];
    const float* b1   = (const float*)d_in[5];
    const float* W2   = (const float*)d_in[6];
    const float* b2   = (const float*)d_in[7];
    const float* bg   = (const float*)d_in[8];
    const float* temp = (const float*)d_in[9];
    const float* Wo   = (const float*)d_in[10];
    const float* bo   = (const float*)d_in[11];
    float* out = (float*)d_out;

    char* w = (char*)d_ws;
    size_t used = 0;
    auto alloc = [&](size_t bytes) {
        char* p = w + used;
        used += (bytes + 255) & ~(size_t)255;
        return p;
    };
    // deg, cvec, flag contiguous -> single memset zeroes all three
    int*    deg    = (int*)alloc(N_NODES * 4);
    float*  cvec   = (float*)alloc(OUT_F * 4);
    int*    flag   = (int*)alloc(4);
    int*    offs   = (int*)alloc((N_NODES + 2) * 4);
    int*    cursor = (int*)alloc(N_NODES * 4);
    int*    srcs   = (int*)alloc(N_EDGES * 4);
    int*    bsum   = (int*)alloc(128 * 4);
    int*    bbase  = (int*)alloc(128 * 4);
    float*  invd   = (float*)alloc(N_NODES * 4);
    float*  mbuf   = (float*)alloc((size_t)NB * N_NODES * 4);
    float*  gates  = (float*)alloc(64 * 4);
    float*  u      = (float*)alloc(NB * OUT_F * 4);
    ushort* WcT    = (ushort*)alloc((size_t)NB * IN_F * OUT_F * 2);
    ushort* WzT    = (ushort*)alloc((size_t)NB * OUT_F * OUT_F * 2);
    ushort* xb     = (ushort*)alloc((size_t)N_NODES * IN_F * 2);
    ushort* X1b    = (ushort*)alloc((size_t)N_NODES * IN_F * 2);
    ushort* X2b    = (ushort*)alloc((size_t)N_NODES * IN_F * 2);
    ushort* X3b    = (ushort*)alloc((size_t)N_NODES * IN_F * 2);
    ushort* R      = (ushort*)alloc((size_t)N_NODES * NB * OUT_F * 2);
    if (used > ws_size) return;

    float* m0v = mbuf;
    float* m1v = mbuf + N_NODES;
    float* m2v = mbuf + 2 * N_NODES;
    float* m3v = mbuf + 3 * N_NODES;

    hipMemsetAsync(deg, 0, N_NODES * 4 + 512 + 256, stream);  // deg + cvec + flag

    detect_kernel<<<1, 64, 0, stream>>>(ei, flag);
    count_kernel<<<N_EDGES / 256, 256, 0, stream>>>(ei, flag, deg);
    scan1_kernel<<<N_NODES / 256, 256, 0, stream>>>(deg, bsum);
    scan2_kernel<<<1, 128, 0, stream>>>(bsum, bbase, offs);
    scan3_kernel<<<N_NODES / 256, 256, 0, stream>>>(deg, bbase, offs, cursor, invd, m0v, m1v);
    fill_csr_kernel<<<N_EDGES / 256, 256, 0, stream>>>(ei, flag, cursor, srcs);

    prep_small_kernel<<<2 * NB, 512, 0, stream>>>(bg, temp, bb, W1, b2, Wo, bo, gates, u, cvec);
    prep_w_kernel<<<NB * IN_F + NB * OUT_F, 128, 0, stream>>>(Wb, W1, W2, Wo, gates, WcT, WzT);
    convert_bf16_kernel<<<(N_NODES * IN_F / 4) / 256, 256, 0, stream>>>(x, xb);

    // fused X + m propagation: X1=A.x (with m2=A.m1), X2=A.X1 (with m3=A.m2), X3=A.X2
    prop_fused_kernel<<<N_NODES / 4 + N_NODES / 256, 256, 0, stream>>>(
        xb, X1b, m1v, m2v, 1, offs, srcs, invd);
    prop_fused_kernel<<<N_NODES / 4 + N_NODES / 256, 256, 0, stream>>>(
        X1b, X2b, m2v, m3v, 1, offs, srcs, invd);
    prop_fused_kernel<<<N_NODES / 4, 256, 0, stream>>>(
        X2b, X3b, (const float*)nullptr, (float*)nullptr, 0, offs, srcs, invd);

    {
        dim3 grid(N_NODES / 128, NB);
        gemm1_mfma_kernel<<<grid, 256, 0, stream>>>(xb, X1b, X2b, X3b, WcT, u, b1, mbuf, R);
    }
    gemm2_mfma_kernel<<<N_NODES / 128, 256, 0, stream>>>(R, WzT, cvec, out);
}

// Round 6
// 308.423 us; speedup vs baseline: 2.2270x; 1.1080x over previous
//
#include <hip/hip_runtime.h>
#include <math.h>

#define N_NODES 32768
#define N_EDGES 524288
#define IN_F    256
#define OUT_F   128
#define NB      4

typedef __attribute__((ext_vector_type(8))) short bf16x8;
typedef __attribute__((ext_vector_type(4))) float f32x4;

__device__ __forceinline__ ushort f2b(float f) {  // f32 -> bf16 RNE
    uint u = __float_as_uint(f);
    return (ushort)((u + 0x7fffu + ((u >> 16) & 1u)) >> 16);
}
__device__ __forceinline__ float b2f_lo(uint v) { return __uint_as_float(v << 16); }
__device__ __forceinline__ float b2f_hi(uint v) { return __uint_as_float(v & 0xffff0000u); }

__device__ __forceinline__ float softmax_gate(const float* bg, const float* temp, int i) {
    float T = temp[0];
    float mx = fmaxf(fmaxf(bg[0], bg[1]), fmaxf(bg[2], bg[3]));
    float e0 = expf((bg[0] - mx) / T), e1 = expf((bg[1] - mx) / T);
    float e2 = expf((bg[2] - mx) / T), e3 = expf((bg[3] - mx) / T);
    float s = e0 + e1 + e2 + e3;
    float ei = (i == 0) ? e0 : (i == 1) ? e1 : (i == 2) ? e2 : e3;
    return ei / s;
}

// ---------------------------------------------------------------------------
// detect int64 vs int32 edge layout
// ---------------------------------------------------------------------------
__global__ void detect_kernel(const int* __restrict__ ei, int* __restrict__ flag) {
    int t = threadIdx.x;  // 64 threads
    if (ei[2 * t + 1] != 0) atomicOr(flag, 1);  // 1 -> int32 layout
}

// blocks [0,2048): degree count; blocks [2048,10240): x f32 -> bf16
__global__ __launch_bounds__(256) void count_conv_kernel(
    const int* __restrict__ ei, const int* __restrict__ flag, int* __restrict__ deg,
    const float* __restrict__ x, ushort* __restrict__ xb) {
    int b = blockIdx.x;
    if (b < N_EDGES / 256) {
        int e = b * 256 + threadIdx.x;
        int c = (*flag == 0) ? ei[2 * (N_EDGES + e)] : ei[N_EDGES + e];
        atomicAdd(&deg[c], 1);
    } else {
        int idx = (b - N_EDGES / 256) * 256 + threadIdx.x;  // 4 floats each
        float4 v = ((const float4*)x)[idx];
        ushort4 o;
        o.x = f2b(v.x); o.y = f2b(v.y); o.z = f2b(v.z); o.w = f2b(v.w);
        ((ushort4*)xb)[idx] = o;
    }
}

// ---------------------------------------------------------------------------
// 3-phase parallel exclusive scan of deg[32768]
// ---------------------------------------------------------------------------
__global__ __launch_bounds__(256) void scan1_kernel(const int* __restrict__ deg,
                                                    int* __restrict__ bsum) {
    int t = threadIdx.x;
    int v = deg[blockIdx.x * 256 + t];
    __shared__ int red[4];
    int lane = t & 63, wv = t >> 6;
#pragma unroll
    for (int off = 32; off > 0; off >>= 1) v += __shfl_down(v, off);
    if (lane == 0) red[wv] = v;
    __syncthreads();
    if (t == 0) bsum[blockIdx.x] = red[0] + red[1] + red[2] + red[3];
}

__global__ __launch_bounds__(128) void scan2_kernel(const int* __restrict__ bsum,
                                                    int* __restrict__ bbase,
                                                    int* __restrict__ offs) {
    __shared__ int s[128];
    int t = threadIdx.x;
    int v = bsum[t];
    s[t] = v;
    __syncthreads();
    for (int off = 1; off < 128; off <<= 1) {
        int add = (t >= off) ? s[t - off] : 0;
        __syncthreads();
        s[t] += add;
        __syncthreads();
    }
    bbase[t] = s[t] - v;
    if (t == 127) offs[N_NODES] = s[127];
}

__global__ __launch_bounds__(256) void scan3_kernel(
    const int* __restrict__ deg, const int* __restrict__ bbase,
    int* __restrict__ offs, int* __restrict__ cursor,
    float* __restrict__ invd, float* __restrict__ m1) {
    __shared__ int s[256];
    int t = threadIdx.x;
    int idx = blockIdx.x * 256 + t;
    int d = deg[idx];
    s[t] = d;
    __syncthreads();
    for (int off = 1; off < 256; off <<= 1) {
        int add = (t >= off) ? s[t - off] : 0;
        __syncthreads();
        s[t] += add;
        __syncthreads();
    }
    int excl = bbase[blockIdx.x] + s[t] - d;
    offs[idx] = excl;
    cursor[idx] = excl;
    invd[idx] = 1.0f / (float)((d > 1) ? d : 1);
    m1[idx] = (d > 0) ? 1.0f : 0.0f;  // A . ones
}

// ---------------------------------------------------------------------------
// Fused: blocks [0,2048) fill CSR; [2048,2112) WcT; [2112,2144) WzT;
// [2144,2152) u / cvec.   256 threads each.
// ---------------------------------------------------------------------------
__global__ __launch_bounds__(256) void fill_prep_kernel(
    const int* __restrict__ ei, const int* __restrict__ flag,
    int* __restrict__ cursor, int* __restrict__ srcs,
    const float* __restrict__ Wb, const float* __restrict__ W1,
    const float* __restrict__ W2, const float* __restrict__ Wo,
    const float* __restrict__ bb, const float* __restrict__ b2,
    const float* __restrict__ bo, const float* __restrict__ bg,
    const float* __restrict__ temp,
    ushort* __restrict__ WcT, ushort* __restrict__ WzT,
    float* __restrict__ u, float* __restrict__ cvec) {
    __shared__ float smem[16 * 128];
    int b = blockIdx.x;
    int tid = threadIdx.x;
    if (b < N_EDGES / 256) {  // ---- fill CSR
        int e = b * 256 + tid;
        int r, c;
        if (*flag == 0) { r = ei[2 * e]; c = ei[2 * (N_EDGES + e)]; }
        else            { r = ei[e];     c = ei[N_EDGES + e]; }
        int slot = atomicAdd(&cursor[c], 1);
        srcs[slot] = r;
        return;
    }
    int f = tid & 127, rh = tid >> 7;
    if (b < N_EDGES / 256 + 64) {  // ---- WcT[i][f][k] = sum_j Wb[i][k][j]*W1[i][j][f]
        int id = b - N_EDGES / 256;
        int i = id >> 4, k0 = (id & 15) * 16;
#pragma unroll
        for (int rr = 0; rr < 8; rr++)
            smem[(rh * 8 + rr) * 128 + f] = Wb[((size_t)i * IN_F + k0 + rh * 8 + rr) * OUT_F + f];
        __syncthreads();
        float acc[8] = {};
        const float* W1i = W1 + (size_t)i * OUT_F * OUT_F;
        for (int j = 0; j < OUT_F; j++) {
            float w1 = W1i[j * OUT_F + f];
#pragma unroll
            for (int rr = 0; rr < 8; rr++) acc[rr] += smem[(rh * 8 + rr) * 128 + j] * w1;
        }
        ushort tmp[8];
#pragma unroll
        for (int rr = 0; rr < 8; rr++) tmp[rr] = f2b(acc[rr]);
        *(uint4*)(WcT + ((size_t)i * OUT_F + f) * IN_F + k0 + rh * 8) = *(uint4*)tmp;
    } else if (b < N_EDGES / 256 + 96) {  // ---- WzT[f][128i+j] = g_i*sum_l W2[i][j][l]*Wo[128i+l][f]
        int id = b - (N_EDGES / 256 + 64);
        int i = id >> 3, j0 = (id & 7) * 16;
#pragma unroll
        for (int rr = 0; rr < 8; rr++)
            smem[(rh * 8 + rr) * 128 + f] = W2[((size_t)i * OUT_F + j0 + rh * 8 + rr) * OUT_F + f];
        __syncthreads();
        float acc[8] = {};
        for (int l = 0; l < OUT_F; l++) {
            float wo = Wo[((size_t)i * OUT_F + l) * OUT_F + f];
#pragma unroll
            for (int rr = 0; rr < 8; rr++) acc[rr] += smem[(rh * 8 + rr) * 128 + l] * wo;
        }
        float g = softmax_gate(bg, temp, i);
        ushort tmp[8];
#pragma unroll
        for (int rr = 0; rr < 8; rr++) tmp[rr] = f2b(g * acc[rr]);
        *(uint4*)(WzT + (size_t)f * (NB * OUT_F) + i * OUT_F + j0 + rh * 8) = *(uint4*)tmp;
    } else {  // ---- u_i = bb_i @ W1_i  (blocks 0..3) / cvec (blocks 4..7, atomic)
        int id = b - (N_EDGES / 256 + 96);
        int jc = rh;  // 0/1, 64 j each
        if (id < NB) {
            int i = id;
            float partial = 0.f;
            for (int j = jc * 64; j < jc * 64 + 64; j++)
                partial += bb[i * OUT_F + j] * W1[((size_t)i * OUT_F + j) * OUT_F + f];
            smem[jc * 128 + f] = partial;
            __syncthreads();
            if (jc == 0) u[i * OUT_F + f] = smem[f] + smem[128 + f];
        } else {
            int i = id - NB;
            float partial = 0.f;
            for (int j = jc * 64; j < jc * 64 + 64; j++)
                partial += b2[i * OUT_F + j] * Wo[((size_t)i * OUT_F + j) * OUT_F + f];
            smem[jc * 128 + f] = partial;
            __syncthreads();
            if (jc == 0) {
                float tot = (smem[f] + smem[128 + f]) * softmax_gate(bg, temp, i);
                if (i == 0) tot += bo[f];
                atomicAdd(&cvec[f], tot);
            }
        }
    }
}

// ---------------------------------------------------------------------------
// Gather macro bodies (256-dim rows, bf16): one wave per node, 2 half-waves,
// up to 8 edges/iter.
// ---------------------------------------------------------------------------
#define GATHER_256(INBUF)                                                       \
    float a0[8] = {0.f,0.f,0.f,0.f,0.f,0.f,0.f,0.f};                            \
    float a1[8] = {0.f,0.f,0.f,0.f,0.f,0.f,0.f,0.f};                            \
    int p = s;                                                                  \
    for (; p + 8 <= e; p += 8) {                                                \
        int base = p + 4 * half;                                                \
        int2 s01 = *(const int2*)(srcs + base);                                 \
        int2 s23 = *(const int2*)(srcs + base + 2);                             \
        uint4 v0 = *(const uint4*)(INBUF + (size_t)s01.x * IN_F + fl * 8);      \
        uint4 v1 = *(const uint4*)(INBUF + (size_t)s01.y * IN_F + fl * 8);      \
        uint4 v2 = *(const uint4*)(INBUF + (size_t)s23.x * IN_F + fl * 8);      \
        uint4 v3 = *(const uint4*)(INBUF + (size_t)s23.y * IN_F + fl * 8);      \
        ACC8(a0, v0); ACC8(a1, v1); ACC8(a0, v2); ACC8(a1, v3);                 \
    }                                                                           \
    for (; p + 4 <= e; p += 4) {                                                \
        int2 ss = *(const int2*)(srcs + p + 2 * half);                          \
        uint4 v0 = *(const uint4*)(INBUF + (size_t)ss.x * IN_F + fl * 8);       \
        uint4 v1 = *(const uint4*)(INBUF + (size_t)ss.y * IN_F + fl * 8);       \
        ACC8(a0, v0); ACC8(a1, v1);                                             \
    }                                                                           \
    for (; p + half < e; p += 2) {                                              \
        int src = srcs[p + half];                                               \
        uint4 v0 = *(const uint4*)(INBUF + (size_t)src * IN_F + fl * 8);        \
        ACC8(a0, v0);                                                           \
    }                                                                           \
    _Pragma("unroll") for (int k = 0; k < 8; k++) a0[k] += a1[k];               \
    _Pragma("unroll") for (int k = 0; k < 8; k++) a0[k] += __shfl_down(a0[k], 32);

#define ACC8(A, V)                                                              \
    A[0] += b2f_lo(V.x); A[1] += b2f_hi(V.x);                                   \
    A[2] += b2f_lo(V.y); A[3] += b2f_hi(V.y);                                   \
    A[4] += b2f_lo(V.z); A[5] += b2f_hi(V.z);                                   \
    A[6] += b2f_lo(V.w); A[7] += b2f_hi(V.w)

// prop1: X1 = A.x (256-dim) + m2 = A.m1 (blocks >= 8192)
__global__ __launch_bounds__(256) void prop_x_kernel(
    const ushort* __restrict__ in, ushort* __restrict__ out,
    const float* __restrict__ m_in, float* __restrict__ m_out,
    const int* __restrict__ offs, const int* __restrict__ srcs,
    const float* __restrict__ invd) {
    int blk = blockIdx.x;
    if (blk >= N_NODES / 4) {
        int n = (blk - N_NODES / 4) * 256 + threadIdx.x;
        int s = offs[n], e = offs[n + 1];
        float sum = 0.f;
        for (int p = s; p < e; ++p) sum += m_in[srcs[p]];
        m_out[n] = sum * invd[n];
        return;
    }
    int node = blk * 4 + (threadIdx.x >> 6);
    int lane = threadIdx.x & 63;
    int half = lane >> 5, fl = lane & 31;
    int s = offs[node], e = offs[node + 1];
    GATHER_256(in);
    if (half == 0) {
        float w = invd[node];
        uint4 o;
        o.x = (uint)f2b(a0[0] * w) | ((uint)f2b(a0[1] * w) << 16);
        o.y = (uint)f2b(a0[2] * w) | ((uint)f2b(a0[3] * w) << 16);
        o.z = (uint)f2b(a0[4] * w) | ((uint)f2b(a0[5] * w) << 16);
        o.w = (uint)f2b(a0[6] * w) | ((uint)f2b(a0[7] * w) << 16);
        *(uint4*)(out + (size_t)node * IN_F + fl * 8) = o;
    }
}

// prop2 on PQ = [P2 | Q3]: P-half gets branch-2 epilogue -> R[:,256:384];
// Q-half raw -> Qp. Blocks >= 8192: m3 = A.m2.
__global__ __launch_bounds__(256) void prop_pq_kernel(
    const ushort* __restrict__ PQ, ushort* __restrict__ R, ushort* __restrict__ Qp,
    const float* __restrict__ m2, float* __restrict__ m3,
    const float* __restrict__ u2, const float* __restrict__ b12,
    const int* __restrict__ offs, const int* __restrict__ srcs,
    const float* __restrict__ invd) {
    int blk = blockIdx.x;
    if (blk >= N_NODES / 4) {
        int n = (blk - N_NODES / 4) * 256 + threadIdx.x;
        int s = offs[n], e = offs[n + 1];
        float sum = 0.f;
        for (int p = s; p < e; ++p) sum += m2[srcs[p]];
        m3[n] = sum * invd[n];
        return;
    }
    int node = blk * 4 + (threadIdx.x >> 6);
    int lane = threadIdx.x & 63;
    int half = lane >> 5, fl = lane & 31;
    int s = offs[node], e = offs[node + 1];
    GATHER_256(PQ);
    if (half == 0) {
        float w = invd[node];
        if (fl < 16) {  // branch 2: relu(A.P2 + m2*u2 + b1_2) -> R col 256+
            int col = fl * 8;
            float mv = m2[node];
            float4 ua = *(const float4*)(u2 + col);
            float4 ub = *(const float4*)(u2 + col + 4);
            float4 ba = *(const float4*)(b12 + col);
            float4 bb_ = *(const float4*)(b12 + col + 4);
            float o_[8];
            o_[0] = fmaxf(a0[0] * w + mv * ua.x + ba.x, 0.f);
            o_[1] = fmaxf(a0[1] * w + mv * ua.y + ba.y, 0.f);
            o_[2] = fmaxf(a0[2] * w + mv * ua.z + ba.z, 0.f);
            o_[3] = fmaxf(a0[3] * w + mv * ua.w + ba.w, 0.f);
            o_[4] = fmaxf(a0[4] * w + mv * ub.x + bb_.x, 0.f);
            o_[5] = fmaxf(a0[5] * w + mv * ub.y + bb_.y, 0.f);
            o_[6] = fmaxf(a0[6] * w + mv * ub.z + bb_.z, 0.f);
            o_[7] = fmaxf(a0[7] * w + mv * ub.w + bb_.w, 0.f);
            uint4 o;
            o.x = (uint)f2b(o_[0]) | ((uint)f2b(o_[1]) << 16);
            o.y = (uint)f2b(o_[2]) | ((uint)f2b(o_[3]) << 16);
            o.z = (uint)f2b(o_[4]) | ((uint)f2b(o_[5]) << 16);
            o.w = (uint)f2b(o_[6]) | ((uint)f2b(o_[7]) << 16);
            *(uint4*)(R + (size_t)node * (NB * OUT_F) + 2 * OUT_F + col) = o;
        } else {  // branch 3 intermediate: Q' = A.Q3 raw
            int col = (fl - 16) * 8;
            uint4 o;
            o.x = (uint)f2b(a0[0] * w) | ((uint)f2b(a0[1] * w) << 16);
            o.y = (uint)f2b(a0[2] * w) | ((uint)f2b(a0[3] * w) << 16);
            o.z = (uint)f2b(a0[4] * w) | ((uint)f2b(a0[5] * w) << 16);
            o.w = (uint)f2b(a0[6] * w) | ((uint)f2b(a0[7] * w) << 16);
            *(uint4*)(Qp + (size_t)node * OUT_F + col) = o;
        }
    }
}

// prop3 on Qp (128-dim rows, 256 B): quarter-wave per edge, branch-3 epilogue
__global__ __launch_bounds__(256) void prop_q_kernel(
    const ushort* __restrict__ Qp, ushort* __restrict__ R,
    const float* __restrict__ m3, const float* __restrict__ u3,
    const float* __restrict__ b13,
    const int* __restrict__ offs, const int* __restrict__ srcs,
    const float* __restrict__ invd) {
    int node = blockIdx.x * 4 + (threadIdx.x >> 6);
    int lane = threadIdx.x & 63;
    int q = lane >> 4, fl = lane & 15;
    int s = offs[node], e = offs[node + 1];
    float a[8] = {0.f,0.f,0.f,0.f,0.f,0.f,0.f,0.f};
    float b[8] = {0.f,0.f,0.f,0.f,0.f,0.f,0.f,0.f};
    int p = s;
    for (; p + 8 <= e; p += 8) {
        int2 ss = *(const int2*)(srcs + p + 2 * q);
        uint4 v0 = *(const uint4*)(Qp + (size_t)ss.x * OUT_F + fl * 8);
        uint4 v1 = *(const uint4*)(Qp + (size_t)ss.y * OUT_F + fl * 8);
        ACC8(a, v0); ACC8(b, v1);
    }
    for (; p + 4 <= e; p += 4) {
        int src = srcs[p + q];
        uint4 v0 = *(const uint4*)(Qp + (size_t)src * OUT_F + fl * 8);
        ACC8(a, v0);
    }
    if (p + q < e) {
        int src = srcs[p + q];
        uint4 v0 = *(const uint4*)(Qp + (size_t)src * OUT_F + fl * 8);
        ACC8(a, v0);
    }
#pragma unroll
    for (int k = 0; k < 8; k++) a[k] += b[k];
#pragma unroll
    for (int k = 0; k < 8; k++) a[k] += __shfl_down(a[k], 32);
#pragma unroll
    for (int k = 0; k < 8; k++) a[k] += __shfl_down(a[k], 16);
    if (lane < 16) {
        float w = invd[node];
        float mv = m3[node];
        int col = fl * 8;
        float4 ua = *(const float4*)(u3 + col);
        float4 ub = *(const float4*)(u3 + col + 4);
        float4 ba = *(const float4*)(b13 + col);
        float4 bb_ = *(const float4*)(b13 + col + 4);
        float o_[8];
        o_[0] = fmaxf(a[0] * w + mv * ua.x + ba.x, 0.f);
        o_[1] = fmaxf(a[1] * w + mv * ua.y + ba.y, 0.f);
        o_[2] = fmaxf(a[2] * w + mv * ua.z + ba.z, 0.f);
        o_[3] = fmaxf(a[3] * w + mv * ua.w + ba.w, 0.f);
        o_[4] = fmaxf(a[4] * w + mv * ub.x + bb_.x, 0.f);
        o_[5] = fmaxf(a[5] * w + mv * ub.y + bb_.y, 0.f);
        o_[6] = fmaxf(a[6] * w + mv * ub.z + bb_.z, 0.f);
        o_[7] = fmaxf(a[7] * w + mv * ub.w + bb_.w, 0.f);
        uint4 o;
        o.x = (uint)f2b(o_[0]) | ((uint)f2b(o_[1]) << 16);
        o.y = (uint)f2b(o_[2]) | ((uint)f2b(o_[3]) << 16);
        o.z = (uint)f2b(o_[4]) | ((uint)f2b(o_[5]) << 16);
        o.w = (uint)f2b(o_[6]) | ((uint)f2b(o_[7]) << 16);
        *(uint4*)(R + (size_t)node * (NB * OUT_F) + 3 * OUT_F + col) = o;
    }
}

// ---------------------------------------------------------------------------
// gemmP (MFMA): y=0: relu(xb.Wc0 + u0 + b1_0) -> R[:,0:128]
//               y=1: relu(X1.Wc1 + m1*u1 + b1_1) -> R[:,128:256]
//               y=2: X1.Wc2 raw -> PQ[:,0:128];  y=3: X1.Wc3 raw -> PQ[:,128:256]
// ---------------------------------------------------------------------------
__global__ __launch_bounds__(256) void gemmP_kernel(
    const ushort* __restrict__ xb, const ushort* __restrict__ X1b,
    const ushort* __restrict__ WcT, const float* __restrict__ u,
    const float* __restrict__ b1, const float* __restrict__ m1,
    ushort* __restrict__ R, ushort* __restrict__ PQ) {
    int y = blockIdx.y;
    const ushort* A = (y == 0) ? xb : X1b;
    const ushort* WT = WcT + (size_t)y * OUT_F * IN_F;
    int m0 = blockIdx.x * 128;

    __shared__ ushort As[128][72];
    __shared__ ushort Bs[128][72];

    int tid = threadIdx.x;
    int wv = tid >> 6, lane = tid & 63, quad = lane >> 4, lm = lane & 15;

    f32x4 acc[2][8];
    f32x4 zero = {0.f, 0.f, 0.f, 0.f};
#pragma unroll
    for (int i = 0; i < 2; i++)
#pragma unroll
        for (int j = 0; j < 8; j++) acc[i][j] = zero;

    for (int k0 = 0; k0 < IN_F; k0 += 64) {
        __syncthreads();
#pragma unroll
        for (int it = 0; it < 4; it++) {
            int c = tid + 256 * it;
            int r = c >> 3, c8 = c & 7;
            *(uint4*)&As[r][c8 * 8] = *(const uint4*)(A + (size_t)(m0 + r) * IN_F + k0 + c8 * 8);
            *(uint4*)&Bs[r][c8 * 8] = *(const uint4*)(WT + (size_t)r * IN_F + k0 + c8 * 8);
        }
        __syncthreads();
#pragma unroll
        for (int ks = 0; ks < 2; ks++) {
            bf16x8 af0 = *(const bf16x8*)&As[wv * 32 + lm][ks * 32 + quad * 8];
            bf16x8 af1 = *(const bf16x8*)&As[wv * 32 + 16 + lm][ks * 32 + quad * 8];
#pragma unroll
            for (int nt = 0; nt < 8; nt++) {
                bf16x8 bf = *(const bf16x8*)&Bs[nt * 16 + lm][ks * 32 + quad * 8];
                acc[0][nt] = __builtin_amdgcn_mfma_f32_16x16x32_bf16(af0, bf, acc[0][nt], 0, 0, 0);
                acc[1][nt] = __builtin_amdgcn_mfma_f32_16x16x32_bf16(af1, bf, acc[1][nt], 0, 0, 0);
            }
        }
    }

    if (y >= 2) {  // raw bf16 -> PQ
        int pqoff = (y - 2) * OUT_F;
#pragma unroll
        for (int mt = 0; mt < 2; mt++)
#pragma unroll
            for (int r = 0; r < 4; r++) {
                int row = m0 + wv * 32 + mt * 16 + quad * 4 + r;
#pragma unroll
                for (int nt = 0; nt < 8; nt++) {
                    int col = nt * 16 + lm;
                    PQ[(size_t)row * IN_F + pqoff + col] = f2b(acc[mt][nt][r]);
                }
            }
    } else {
        float uv[8], bv[8];
#pragma unroll
        for (int nt = 0; nt < 8; nt++) {
            int col = nt * 16 + lm;
            uv[nt] = u[y * OUT_F + col];
            bv[nt] = b1[y * OUT_F + col];
        }
#pragma unroll
        for (int mt = 0; mt < 2; mt++)
#pragma unroll
            for (int r = 0; r < 4; r++) {
                int row = m0 + wv * 32 + mt * 16 + quad * 4 + r;
                float mval = (y == 0) ? 1.0f : m1[row];
#pragma unroll
                for (int nt = 0; nt < 8; nt++) {
                    int col = nt * 16 + lm;
                    float h = acc[mt][nt][r] + mval * uv[nt] + bv[nt];
                    R[(size_t)row * (NB * OUT_F) + y * OUT_F + col] = f2b(fmaxf(h, 0.f));
                }
            }
    }
}

// ---------------------------------------------------------------------------
// GEMM2 (MFMA): out = R[32768,512](bf16) @ Wz(bf16) + c  -> f32
// ---------------------------------------------------------------------------
__global__ __launch_bounds__(256) void gemm2_mfma_kernel(
    const ushort* __restrict__ R, const ushort* __restrict__ WzT,
    const float* __restrict__ cvec, float* __restrict__ out) {
    int m0 = blockIdx.x * 128;
    const int K = NB * OUT_F;  // 512

    __shared__ ushort As[128][72];
    __shared__ ushort Bs[128][72];

    int tid = threadIdx.x;
    int wv = tid >> 6, lane = tid & 63, quad = lane >> 4, lm = lane & 15;

    f32x4 acc[2][8];
    f32x4 zero = {0.f, 0.f, 0.f, 0.f};
#pragma unroll
    for (int i = 0; i < 2; i++)
#pragma unroll
        for (int j = 0; j < 8; j++) acc[i][j] = zero;

    for (int k0 = 0; k0 < K; k0 += 64) {
        __syncthreads();
#pragma unroll
        for (int it = 0; it < 4; it++) {
            int c = tid + 256 * it;
            int r = c >> 3, c8 = c & 7;
            *(uint4*)&As[r][c8 * 8] = *(const uint4*)(R + (size_t)(m0 + r) * K + k0 + c8 * 8);
            *(uint4*)&Bs[r][c8 * 8] = *(const uint4*)(WzT + (size_t)r * K + k0 + c8 * 8);
        }
        __syncthreads();
#pragma unroll
        for (int ks = 0; ks < 2; ks++) {
            bf16x8 af0 = *(const bf16x8*)&As[wv * 32 + lm][ks * 32 + quad * 8];
            bf16x8 af1 = *(const bf16x8*)&As[wv * 32 + 16 + lm][ks * 32 + quad * 8];
#pragma unroll
            for (int nt = 0; nt < 8; nt++) {
                bf16x8 bf = *(const bf16x8*)&Bs[nt * 16 + lm][ks * 32 + quad * 8];
                acc[0][nt] = __builtin_amdgcn_mfma_f32_16x16x32_bf16(af0, bf, acc[0][nt], 0, 0, 0);
                acc[1][nt] = __builtin_amdgcn_mfma_f32_16x16x32_bf16(af1, bf, acc[1][nt], 0, 0, 0);
            }
        }
    }

    float cb[8];
#pragma unroll
    for (int nt = 0; nt < 8; nt++) cb[nt] = cvec[nt * 16 + lm];
#pragma unroll
    for (int mt = 0; mt < 2; mt++)
#pragma unroll
        for (int r = 0; r < 4; r++) {
            int row = m0 + wv * 32 + mt * 16 + quad * 4 + r;
#pragma unroll
            for (int nt = 0; nt < 8; nt++) {
                int col = nt * 16 + lm;
                out[(size_t)row * OUT_F + col] = acc[mt][nt][r] + cb[nt];
            }
        }
}

// ---------------------------------------------------------------------------
extern "C" void kernel_launch(void* const* d_in, const int* in_sizes, int n_in,
                              void* d_out, int out_size, void* d_ws, size_t ws_size,
                              hipStream_t stream) {
    const float* x    = (const float*)d_in[0];
    const int*   ei   = (const int*)d_in[1];
    const float* Wb   = (const float*)d_in[2];
    const float* bb   = (const float*)d_in[3];
    const float* W1   = (const float*)d_in[4];
    const float* b1   = (const float*)d_in[5];
    const float* W2   = (const float*)d_in[6];
    const float* b2   = (const float*)d_in[7];
    const float* bg   = (const float*)d_in[8];
    const float* temp = (const float*)d_in[9];
    const float* Wo   = (const float*)d_in[10];
    const float* bo   = (const float*)d_in[11];
    float* out = (float*)d_out;

    char* w = (char*)d_ws;
    size_t used = 0;
    auto alloc = [&](size_t bytes) {
        char* p = w + used;
        used += (bytes + 255) & ~(size_t)255;
        return p;
    };
    // deg, cvec, flag contiguous -> single memset zeroes all three
    int*    deg    = (int*)alloc(N_NODES * 4);
    float*  cvec   = (float*)alloc(OUT_F * 4);
    int*    flag   = (int*)alloc(4);
    int*    offs   = (int*)alloc((N_NODES + 2) * 4);
    int*    cursor = (int*)alloc(N_NODES * 4);
    int*    srcs   = (int*)alloc(N_EDGES * 4);
    int*    bsum   = (int*)alloc(128 * 4);
    int*    bbase  = (int*)alloc(128 * 4);
    float*  invd   = (float*)alloc(N_NODES * 4);
    float*  mbuf   = (float*)alloc((size_t)3 * N_NODES * 4);
    float*  u      = (float*)alloc(NB * OUT_F * 4);
    ushort* WcT    = (ushort*)alloc((size_t)NB * IN_F * OUT_F * 2);
    ushort* WzT    = (ushort*)alloc((size_t)NB * OUT_F * OUT_F * 2);
    ushort* xb     = (ushort*)alloc((size_t)N_NODES * IN_F * 2);
    ushort* X1b    = (ushort*)alloc((size_t)N_NODES * IN_F * 2);
    ushort* PQ     = (ushort*)alloc((size_t)N_NODES * IN_F * 2);
    ushort* Qp     = (ushort*)alloc((size_t)N_NODES * OUT_F * 2);
    ushort* R      = (ushort*)alloc((size_t)N_NODES * NB * OUT_F * 2);
    if (used > ws_size) return;

    float* m1v = mbuf;
    float* m2v = mbuf + N_NODES;
    float* m3v = mbuf + 2 * N_NODES;

    hipMemsetAsync(deg, 0, N_NODES * 4 + 512 + 256, stream);  // deg + cvec + flag

    detect_kernel<<<1, 64, 0, stream>>>(ei, flag);
    count_conv_kernel<<<N_EDGES / 256 + N_NODES * IN_F / 1024, 256, 0, stream>>>(
        ei, flag, deg, x, xb);
    scan1_kernel<<<N_NODES / 256, 256, 0, stream>>>(deg, bsum);
    scan2_kernel<<<1, 128, 0, stream>>>(bsum, bbase, offs);
    scan3_kernel<<<N_NODES / 256, 256, 0, stream>>>(deg, bbase, offs, cursor, invd, m1v);
    fill_prep_kernel<<<N_EDGES / 256 + 64 + 32 + 8, 256, 0, stream>>>(
        ei, flag, cursor, srcs, Wb, W1, W2, Wo, bb, b2, bo, bg, temp, WcT, WzT, u, cvec);

    // X1 = A.x  (+ m2 = A.m1)
    prop_x_kernel<<<N_NODES / 4 + N_NODES / 256, 256, 0, stream>>>(
        xb, X1b, m1v, m2v, offs, srcs, invd);
    // branches 0,1 final; P2/Q3 staging for branches 2,3
    {
        dim3 grid(N_NODES / 128, NB);
        gemmP_kernel<<<grid, 256, 0, stream>>>(xb, X1b, WcT, u, b1, m1v, R, PQ);
    }
    // A.[P2|Q3]: branch-2 epilogue -> R, Q' -> Qp  (+ m3 = A.m2)
    prop_pq_kernel<<<N_NODES / 4 + N_NODES / 256, 256, 0, stream>>>(
        PQ, R, Qp, m2v, m3v, u + 2 * OUT_F, b1 + 2 * OUT_F, offs, srcs, invd);
    // A.Q' with branch-3 epilogue -> R (128-dim gather: half traffic)
    prop_q_kernel<<<N_NODES / 4, 256, 0, stream>>>(
        Qp, R, m3v, u + 3 * OUT_F, b1 + 3 * OUT_F, offs, srcs, invd);

    gemm2_mfma_kernel<<<N_NODES / 128, 256, 0, stream>>>(R, WzT, cvec, out);
}